// Round 7
// baseline (131.824 us; speedup 1.0000x reference)
//
#include <hip/hip_runtime.h>
#include <hip/hip_bf16.h>
#include <cstdint>
#include <math.h>

// Problem constants
#define B_DIM 2
#define T_SEQ 2048
#define C_DIM 1024
#define H_NUM 16
#define D_HEAD 64
#define M_ROWS (B_DIM * T_SEQ)      // 4096
#define N_QKV (3 * H_NUM * D_HEAD)  // 3072

using short8  = __attribute__((ext_vector_type(8))) short;
using short4v = __attribute__((ext_vector_type(4))) short;
using f32x4   = __attribute__((ext_vector_type(4))) float;

__device__ __forceinline__ short f2bf(float f) {
  union { __hip_bfloat16 h; short s; } u;
  u.h = __float2bfloat16(f);
  return u.s;
}

// async global->LDS, 16B per lane (m97 pattern: per-lane LDS ptr = base + lane*16B)
__device__ __forceinline__ void gld_lds16(short* lds, const short* g) {
  __builtin_amdgcn_global_load_lds(
      (const unsigned int __attribute__((address_space(1)))*)g,
      (unsigned int __attribute__((address_space(3)))*)lds, 16, 0, 0);
}

// counted-vmcnt barrier cluster (T4, m201-proven): stage loads stay in flight
// across the barrier; lgkmcnt(0) retires this wave's ds_reads before the
// soon-to-be-overwritten buffer is re-staged.
#define BAR_VM4()                                              \
  do {                                                         \
    asm volatile("s_waitcnt vmcnt(4) lgkmcnt(0)" ::: "memory"); \
    __builtin_amdgcn_s_barrier();                              \
    __builtin_amdgcn_sched_barrier(0);                         \
  } while (0)
#define BAR_VM0()                                              \
  do {                                                         \
    asm volatile("s_waitcnt vmcnt(0) lgkmcnt(0)" ::: "memory"); \
    __builtin_amdgcn_s_barrier();                              \
    __builtin_amdgcn_sched_barrier(0);                         \
  } while (0)

// ---------------------------------------------------------------------------
// Kernel 1: f32 -> bf16 cast (vectorized, 8 elems/thread)
// ---------------------------------------------------------------------------
__global__ __launch_bounds__(256) void cvt_f32_bf16(const float* __restrict__ in,
                                                    short* __restrict__ out, int n8) {
  int i = blockIdx.x * 256 + threadIdx.x;
  if (i >= n8) return;
  const float4* p = reinterpret_cast<const float4*>(in) + (size_t)i * 2;
  float4 a = p[0], b = p[1];
  short8 o;
  o[0] = f2bf(a.x); o[1] = f2bf(a.y); o[2] = f2bf(a.z); o[3] = f2bf(a.w);
  o[4] = f2bf(b.x); o[5] = f2bf(b.y); o[6] = f2bf(b.z); o[7] = f2bf(b.w);
  reinterpret_cast<short8*>(out)[i] = o;
}

// ---------------------------------------------------------------------------
// Kernel 2: pack Wq/Wk/Wv [H][C][D] f32 -> Wt [3*H*D][C] bf16 (transposed)
// ---------------------------------------------------------------------------
__global__ __launch_bounds__(256) void pack_w(const float* __restrict__ Wq,
                                              const float* __restrict__ Wk,
                                              const float* __restrict__ Wv,
                                              short* __restrict__ Wt) {
  int bid  = blockIdx.x;
  int proj = bid >> 8;
  int h    = (bid >> 4) & 15;
  int cb   = bid & 15;
  const float* W = (proj == 0) ? Wq : ((proj == 1) ? Wk : Wv);
  const float* src = W + ((size_t)h * C_DIM + (size_t)cb * 64) * D_HEAD;

  __shared__ float tile[64][65];
  int tid = threadIdx.x;

#pragma unroll
  for (int j = 0; j < 4; j++) {
    int flat = tid + j * 256;
    int c    = flat >> 4;
    int d4   = flat & 15;
    float4 v = reinterpret_cast<const float4*>(src + (size_t)c * D_HEAD)[d4];
    tile[c][d4 * 4 + 0] = v.x;
    tile[c][d4 * 4 + 1] = v.y;
    tile[c][d4 * 4 + 2] = v.z;
    tile[c][d4 * 4 + 3] = v.w;
  }
  __syncthreads();

  int d     = tid >> 2;
  int cpart = (tid & 3) * 16;
  short* dst = Wt + ((size_t)(proj * H_NUM + h) * D_HEAD + d) * C_DIM + cb * 64 + cpart;
  short8 o0, o1;
#pragma unroll
  for (int j = 0; j < 8; j++) {
    o0[j] = f2bf(tile[cpart + j][d]);
    o1[j] = f2bf(tile[cpart + 8 + j][d]);
  }
  *reinterpret_cast<short8*>(dst)     = o0;
  *reinterpret_cast<short8*>(dst + 8) = o1;
}

// ---------------------------------------------------------------------------
// GEMM: C[M,N] = A[M,K] @ Bt[N,K]^T, bf16 in, f32 accum.
// 128x128 tile, BK=32, linear LDS, global_load_lds width-16, now with
// 3-deep staging + counted vmcnt(4) (stage k+2 stays in flight across the
// barrier; never vmcnt(0) in the main loop).
// ---------------------------------------------------------------------------
template <int MODE>
__global__ __launch_bounds__(256) void gemm_bt(
    const short* __restrict__ A, const short* __restrict__ Bt,
    const float* __restrict__ bias,
    short* __restrict__ qb, short* __restrict__ kb, short* __restrict__ vtb,
    float* __restrict__ outb,
    int M, int N, int K) {
  constexpr int BK = 32;
  __shared__ short As[3][128 * BK];
  __shared__ short Bs[3][128 * BK];

  int tid  = threadIdx.x;
  int lane = tid & 63;
  int wv   = tid >> 6;
  int q15  = lane & 15, g = lane >> 4;
  int ntn  = N >> 7;
  int bm   = blockIdx.x / ntn;
  int bn   = blockIdx.x % ntn;
  int row0 = bm << 7, col0 = bn << 7;
  int wm   = (wv >> 1) << 6;
  int wn   = (wv & 1) << 6;

  f32x4 acc[4][4];
#pragma unroll
  for (int i = 0; i < 4; i++)
#pragma unroll
    for (int j = 0; j < 4; j++) acc[i][j] = (f32x4){0.f, 0.f, 0.f, 0.f};

  const short* ag = A  + (size_t)(row0 + (tid >> 2)) * K + (tid & 3) * 8;
  const short* bg = Bt + (size_t)(col0 + (tid >> 2)) * K + (tid & 3) * 8;
  const size_t gstep = (size_t)64 * K;

  auto stage = [&](int ks, int buf) {
    const short* a = ag + (size_t)ks * BK;
    const short* bb = bg + (size_t)ks * BK;
    gld_lds16(&As[buf][0] + tid * 8, a);
    gld_lds16(&As[buf][64 * BK] + tid * 8, a + gstep);
    gld_lds16(&Bs[buf][0] + tid * 8, bb);
    gld_lds16(&Bs[buf][64 * BK] + tid * 8, bb + gstep);
  };

  int nk = K / BK;
  stage(0, 0);
  stage(1, 1);
  asm volatile("s_waitcnt vmcnt(4)" ::: "memory");
  __builtin_amdgcn_s_barrier();
  __builtin_amdgcn_sched_barrier(0);

  for (int k = 0; k < nk; ++k) {
    int buf = k % 3;
    if (k + 2 < nk) stage(k + 2, (k + 2) % 3);

    short8 af[4], bf[4];
#pragma unroll
    for (int mi = 0; mi < 4; mi++)
      af[mi] = *reinterpret_cast<const short8*>(
          &As[buf][(wm + mi * 16 + q15) * BK + g * 8]);
#pragma unroll
    for (int ni = 0; ni < 4; ni++)
      bf[ni] = *reinterpret_cast<const short8*>(
          &Bs[buf][(wn + ni * 16 + q15) * BK + g * 8]);
    __builtin_amdgcn_s_setprio(1);
#pragma unroll
    for (int mi = 0; mi < 4; mi++)
#pragma unroll
      for (int ni = 0; ni < 4; ni++)
        acc[mi][ni] = __builtin_amdgcn_mfma_f32_16x16x32_bf16(af[mi], bf[ni],
                                                              acc[mi][ni], 0, 0, 0);
    __builtin_amdgcn_s_setprio(0);

    if (k + 1 < nk) {
      if (k + 2 < nk) BAR_VM4(); else BAR_VM0();
    }
  }

  // epilogue: C/D layout: col = lane&15, row = (lane>>4)*4 + r
#pragma unroll
  for (int mi = 0; mi < 4; mi++) {
#pragma unroll
    for (int ni = 0; ni < 4; ni++) {
      int rb  = row0 + wm + mi * 16 + (g << 2);
      int col = col0 + wn + ni * 16 + q15;
      f32x4 v = acc[mi][ni];
      if (MODE == 0) {
        int proj = col >> 10;
        int hh   = (col >> 6) & (H_NUM - 1);
        int d    = col & (D_HEAD - 1);
        int b    = rb >> 11;
        int t    = rb & (T_SEQ - 1);
        if (proj < 2) {
          float scl = (proj == 0) ? 0.125f : 1.0f;  // fold 1/sqrt(D) into q
          short* dst = (proj == 0 ? qb : kb) +
                       ((size_t)(b * H_NUM + hh) * T_SEQ) * D_HEAD + d;
#pragma unroll
          for (int r = 0; r < 4; r++)
            dst[(size_t)(t + r) * D_HEAD] = f2bf(v[r] * scl);
        } else {
          short4v pk;
#pragma unroll
          for (int r = 0; r < 4; r++) pk[r] = f2bf(v[r]);
          short* dst = vtb + ((size_t)(b * H_NUM + hh) * D_HEAD + d) * T_SEQ + t;
          *reinterpret_cast<short4v*>(dst) = pk;
        }
      } else {
        float bb = bias[col];
#pragma unroll
        for (int r = 0; r < 4; r++)
          outb[(size_t)(rb + r) * N + col] = v[r] + bb;
      }
    }
  }
}

// ---------------------------------------------------------------------------
// Flash attention v7: swapped-operand (S^T = K·Q^T), LDS-staged K/V with
// 3-deep buffers + counted vmcnt(4) (T4): staging latency hides under two
// chunks of compute; the barrier never drains the in-flight prefetch.
// Causal strip-pairing (exactly 33 qt-chunks per wave, all 512 blocks equal).
// ---------------------------------------------------------------------------
__global__ __launch_bounds__(256) void attn_fwd(const short* __restrict__ qg,
                                                const short* __restrict__ kg,
                                                const short* __restrict__ vt,
                                                short* __restrict__ ob) {
  constexpr float LOG2E = 1.44269504f;
  int bid  = blockIdx.x;
  int slot = bid >> 3;                  // 0..63
  int bh   = (bid & 7) * 4 + (slot & 3);
  int ip   = slot >> 2;                 // pair index 0..15
  int b    = bh >> 4;
  int h    = bh & 15;
  int tid  = threadIdx.x, lane = tid & 63, wv = tid >> 6;
  int q15  = lane & 15, g = lane >> 4;
  int qr0  = ip * 64 + wv * 16;               // strip i    (light)
  int qr1  = (31 - ip) * 64 + wv * 16;        // strip 31-i (heavy)

  __shared__ short Kl[3][64 * 64];      // [s][d] swizzled, 8KB per buf
  __shared__ short Vl[3][64 * 64];      // [d][s] swizzled
  __shared__ short Ol[4][32][68];       // epilogue transpose

  const short* qp = qg + (size_t)bh * T_SEQ * D_HEAD;
  const short* kp = kg + (size_t)bh * T_SEQ * D_HEAD;
  const short* vp = vt + (size_t)bh * D_HEAD * T_SEQ;

  // staging geometry (rule #21): LDS written linearly (base + lane*16B);
  // SOURCE colbyte pre-swizzled so data(row, cb) lands at byte row*128 ^ ((row&7)<<4).
  int r8    = lane >> 3;
  int gcb   = ((lane & 7) * 16) ^ (r8 << 4);
  int srow0 = wv * 16;

  // fragment-read offsets (chunk-invariant, shorts)
  int hh = (q15 & 7) << 4;
  int koff0 = ((0 * 64 + g * 16) ^ hh) >> 1;
  int koff1 = ((1 * 64 + g * 16) ^ hh) >> 1;
  int voff[4];
#pragma unroll
  for (int st = 0; st < 4; st++) voff[st] = ((st * 32 + g * 8) ^ hh) >> 1;

  // Q fragments (prescaled by 1/8): lane&15 = q, elems over d
  short8 qf0[2], qf1[2];
#pragma unroll
  for (int kk = 0; kk < 2; kk++) {
    qf0[kk] = *reinterpret_cast<const short8*>(
        qp + (size_t)(qr0 + q15) * D_HEAD + kk * 32 + g * 8);
    qf1[kk] = *reinterpret_cast<const short8*>(
        qp + (size_t)(qr1 + q15) * D_HEAD + kk * 32 + g * 8);
  }

  f32x4 acc0[4], acc1[4];
#pragma unroll
  for (int dt = 0; dt < 4; dt++) {
    acc0[dt] = (f32x4){0.f, 0.f, 0.f, 0.f};
    acc1[dt] = (f32x4){0.f, 0.f, 0.f, 0.f};
  }
  float m0 = -1e30f, l0 = 0.f, m1 = -1e30f, l1 = 0.f;

  int nch = 32 - ip;  // chunks 0..31-ip (qt1's range; superset of qt0's)

  auto stage = [&](int c, int buf) {
    const short* ks = kp + (size_t)(c * 64 + srow0 + r8) * D_HEAD + (gcb >> 1);
    const short* vs = vp + (size_t)(srow0 + r8) * T_SEQ + c * 64 + (gcb >> 1);
    short* kd = &Kl[buf][srow0 * 64] + lane * 8;
    short* vd = &Vl[buf][srow0 * 64] + lane * 8;
    gld_lds16(kd, ks);
    gld_lds16(kd + 8 * 64, ks + (size_t)8 * D_HEAD);
    gld_lds16(vd, vs);
    gld_lds16(vd + 8 * 64, vs + (size_t)8 * T_SEQ);
  };

  // one q-tile's S / softmax / PV for the current chunk (all static indices)
  auto do_tile = [&](short8 (&qfx)[2], f32x4 (&accx)[4], float& mref, float& lref,
                     int qrX, bool masked, int s0,
                     short8 (&kf)[4][2], short4v (&vf)[4][4]) {
    f32x4 sv[4];
    __builtin_amdgcn_s_setprio(1);
#pragma unroll
    for (int st = 0; st < 4; st++) {
      f32x4 s = (f32x4){0.f, 0.f, 0.f, 0.f};
      s = __builtin_amdgcn_mfma_f32_16x16x32_bf16(kf[st][0], qfx[0], s, 0, 0, 0);
      s = __builtin_amdgcn_mfma_f32_16x16x32_bf16(kf[st][1], qfx[1], s, 0, 0, 0);
      sv[st] = s;
    }
    __builtin_amdgcn_s_setprio(0);

    if (masked) {
#pragma unroll
      for (int st = 0; st < 4; st++)
#pragma unroll
        for (int r = 0; r < 4; r++) {
          int sg = s0 + st * 16 + g * 4 + r;
          if (sg > qrX + q15) sv[st][r] = -1e30f;
        }
    }

    float mx = sv[0][0];
#pragma unroll
    for (int st = 0; st < 4; st++)
#pragma unroll
      for (int r = 0; r < 4; r++) mx = fmaxf(mx, sv[st][r]);
    mx = fmaxf(mx, __shfl_xor(mx, 16));
    mx = fmaxf(mx, __shfl_xor(mx, 32));
    if (!__all(mx <= mref + 8.0f)) {  // defer-max (T13)
      float mnew = fmaxf(mref, mx);
      float sc   = __builtin_amdgcn_exp2f((mref - mnew) * LOG2E);
      mref = mnew;
      lref *= sc;
#pragma unroll
      for (int dt = 0; dt < 4; dt++) accx[dt] *= sc;
    }
    float mcur = mref;
    short4v pbf[4];
    float ps = 0.f;
#pragma unroll
    for (int st = 0; st < 4; st++)
#pragma unroll
      for (int r = 0; r < 4; r++) {
        float p = __builtin_amdgcn_exp2f((sv[st][r] - mcur) * LOG2E);
        ps += p;
        pbf[st][r] = f2bf(p);
      }
    ps += __shfl_xor(ps, 16);
    ps += __shfl_xor(ps, 32);
    lref += ps;

    __builtin_amdgcn_s_setprio(1);
#pragma unroll
    for (int st = 0; st < 4; st++)
#pragma unroll
      for (int dt = 0; dt < 4; dt++) {
#if __has_builtin(__builtin_amdgcn_mfma_f32_16x16x16bf16_1k)
        accx[dt] = __builtin_amdgcn_mfma_f32_16x16x16bf16_1k(
            vf[st][dt], pbf[st], accx[dt], 0, 0, 0);
#else
        short4v v4 = vf[st][dt];
        short4v p4 = pbf[st];
        short8 az = (short8){v4[0], v4[1], v4[2], v4[3], 0, 0, 0, 0};
        short8 bz = (short8){p4[0], p4[1], p4[2], p4[3], 0, 0, 0, 0};
        accx[dt] =
            __builtin_amdgcn_mfma_f32_16x16x32_bf16(az, bz, accx[dt], 0, 0, 0);
#endif
      }
    __builtin_amdgcn_s_setprio(0);
  };

  stage(0, 0);
  stage(1, 1);
  asm volatile("s_waitcnt vmcnt(4)" ::: "memory");
  __builtin_amdgcn_s_barrier();
  __builtin_amdgcn_sched_barrier(0);

  for (int c = 0; c < nch; ++c) {
    int s0 = c * 64;
    int buf = c % 3;
    if (c + 2 < nch) stage(c + 2, (c + 2) % 3);

    // shared K/V fragments for both q-tiles
    short8 kf[4][2];
#pragma unroll
    for (int st = 0; st < 4; st++) {
      int rbase = (st * 16 + q15) * 64;
      kf[st][0] = *reinterpret_cast<const short8*>(&Kl[buf][rbase + koff0]);
      kf[st][1] = *reinterpret_cast<const short8*>(&Kl[buf][rbase + koff1]);
    }
    short4v vf[4][4];
#pragma unroll
    for (int st = 0; st < 4; st++)
#pragma unroll
      for (int dt = 0; dt < 4; dt++)
        vf[st][dt] = *reinterpret_cast<const short4v*>(
            &Vl[buf][(dt * 16 + q15) * 64 + voff[st]]);

    do_tile(qf1, acc1, m1, l1, qr1, c == nch - 1, s0, kf, vf);   // heavy strip
    if (c <= ip) do_tile(qf0, acc0, m0, l0, qr0, c == ip, s0, kf, vf);  // light

    if (c + 1 < nch) {
      if (c + 2 < nch) BAR_VM4(); else BAR_VM0();
    }
  }

  // epilogue: per-wave LDS transpose -> coalesced bf16 stores (two strips)
#pragma unroll
  for (int dt = 0; dt < 4; dt++) {
    float i0 = 1.0f / l0, i1 = 1.0f / l1;
#pragma unroll
    for (int r = 0; r < 4; r++) {
      Ol[wv][q15][dt * 16 + g * 4 + r]      = f2bf(acc0[dt][r] * i0);
      Ol[wv][16 + q15][dt * 16 + g * 4 + r] = f2bf(acc1[dt][r] * i1);
    }
  }
  __syncthreads();
  int row = lane >> 1, cb = (lane & 1) * 32;
  int grow = (row < 16) ? (qr0 + row) : (qr1 + row - 16);
  size_t base = ((size_t)(b * T_SEQ) + grow) * C_DIM + h * 64 + cb;
#pragma unroll
  for (int i = 0; i < 4; i++)
    *reinterpret_cast<short8*>(ob + base + i * 8) =
        *reinterpret_cast<const short8*>(&Ol[wv][row][cb + i * 8]);
}

// ---------------------------------------------------------------------------
// Launch. Workspace layout (needs >= 40 MB):
//   [0, 8M)        xb   bf16 x cast            (reused as obuf after QKV GEMM)
//   [8M, 14.3M)    Wt   bf16 packed QKV weights [3072][1024]
//   [14M, 16M)     Wob  bf16 Wo [1024][1024]
//   [16M, 24M)     qb   bf16 [B,H,T,D]  (prescaled by 1/8)
//   [24M, 32M)     kb   bf16 [B,H,T,D]
//   [32M, 40M)     vtb  bf16 [B,H,D,T]
// ---------------------------------------------------------------------------
extern "C" void kernel_launch(void* const* d_in, const int* in_sizes, int n_in,
                              void* d_out, int out_size, void* d_ws, size_t ws_size,
                              hipStream_t stream) {
  const float* x  = (const float*)d_in[0];
  const float* Wq = (const float*)d_in[1];
  const float* Wk = (const float*)d_in[2];
  const float* Wv = (const float*)d_in[3];
  const float* Wo = (const float*)d_in[4];
  const float* bo = (const float*)d_in[5];
  float* out = (float*)d_out;

  char* ws = (char*)d_ws;
  short* xb   = (short*)(ws + 0);
  short* Wt   = (short*)(ws + 8388608);
  short* Wob  = (short*)(ws + 14680064);
  short* qb   = (short*)(ws + 16777216);
  short* kb   = (short*)(ws + 25165824);
  short* vtb  = (short*)(ws + 33554432);
  short* obuf = xb;  // reuse after QKV GEMM consumed xb

  cvt_f32_bf16<<<2048, 256, 0, stream>>>(x, xb, M_ROWS * C_DIM / 8);
  cvt_f32_bf16<<<512, 256, 0, stream>>>(Wo, Wob, C_DIM * C_DIM / 8);
  pack_w<<<768, 256, 0, stream>>>(Wq, Wk, Wv, Wt);

  gemm_bt<0><<<(M_ROWS / 128) * (N_QKV / 128), 256, 0, stream>>>(
      xb, Wt, nullptr, qb, kb, vtb, nullptr, M_ROWS, N_QKV, C_DIM);

  attn_fwd<<<512, 256, 0, stream>>>(qb, kb, vtb, obuf);

  gemm_bt<1><<<(M_ROWS / 128) * (C_DIM / 128), 256, 0, stream>>>(
      obuf, Wob, bo, nullptr, nullptr, nullptr, out, M_ROWS, C_DIM, C_DIM);
}

// Round 8
// 119.135 us; speedup vs baseline: 1.1065x; 1.1065x over previous
//
#include <hip/hip_runtime.h>
#include <hip/hip_bf16.h>
#include <cstdint>
#include <math.h>

// Problem constants
#define B_DIM 2
#define T_SEQ 2048
#define C_DIM 1024
#define H_NUM 16
#define D_HEAD 64
#define M_ROWS (B_DIM * T_SEQ)      // 4096
#define N_QKV (3 * H_NUM * D_HEAD)  // 3072

using short8  = __attribute__((ext_vector_type(8))) short;
using short4v = __attribute__((ext_vector_type(4))) short;
using f32x4   = __attribute__((ext_vector_type(4))) float;

__device__ __forceinline__ short f2bf(float f) {
  union { __hip_bfloat16 h; short s; } u;
  u.h = __float2bfloat16(f);
  return u.s;
}
// truncating f32->bf16 (1 instr): safe for p >= 0 (<=1 ulp, 0.8% rel)
__device__ __forceinline__ short f2bf_trunc(float f) {
  union { float f; unsigned u; } v;
  v.f = f;
  return (short)(v.u >> 16);
}

// async global->LDS, 16B per lane (m97 pattern: per-lane LDS ptr = base + lane*16B)
__device__ __forceinline__ void gld_lds16(short* lds, const short* g) {
  __builtin_amdgcn_global_load_lds(
      (const unsigned int __attribute__((address_space(1)))*)g,
      (unsigned int __attribute__((address_space(3)))*)lds, 16, 0, 0);
}

// counted-vmcnt barrier cluster (T4): loads stay in flight across the barrier.
#define BAR_VM(N)                                                    \
  do {                                                               \
    asm volatile("s_waitcnt vmcnt(" #N ") lgkmcnt(0)" ::: "memory"); \
    __builtin_amdgcn_s_barrier();                                    \
    __builtin_amdgcn_sched_barrier(0);                               \
  } while (0)

// ---------------------------------------------------------------------------
// Kernel 1: f32 -> bf16 cast (vectorized, 8 elems/thread)
// ---------------------------------------------------------------------------
__global__ __launch_bounds__(256) void cvt_f32_bf16(const float* __restrict__ in,
                                                    short* __restrict__ out, int n8) {
  int i = blockIdx.x * 256 + threadIdx.x;
  if (i >= n8) return;
  const float4* p = reinterpret_cast<const float4*>(in) + (size_t)i * 2;
  float4 a = p[0], b = p[1];
  short8 o;
  o[0] = f2bf(a.x); o[1] = f2bf(a.y); o[2] = f2bf(a.z); o[3] = f2bf(a.w);
  o[4] = f2bf(b.x); o[5] = f2bf(b.y); o[6] = f2bf(b.z); o[7] = f2bf(b.w);
  reinterpret_cast<short8*>(out)[i] = o;
}

// ---------------------------------------------------------------------------
// Kernel 2: pack Wq/Wk/Wv [H][C][D] f32 -> Wt [3*H*D][C] bf16 (transposed)
// ---------------------------------------------------------------------------
__global__ __launch_bounds__(256) void pack_w(const float* __restrict__ Wq,
                                              const float* __restrict__ Wk,
                                              const float* __restrict__ Wv,
                                              short* __restrict__ Wt) {
  int bid  = blockIdx.x;
  int proj = bid >> 8;
  int h    = (bid >> 4) & 15;
  int cb   = bid & 15;
  const float* W = (proj == 0) ? Wq : ((proj == 1) ? Wk : Wv);
  const float* src = W + ((size_t)h * C_DIM + (size_t)cb * 64) * D_HEAD;

  __shared__ float tile[64][65];
  int tid = threadIdx.x;

#pragma unroll
  for (int j = 0; j < 4; j++) {
    int flat = tid + j * 256;
    int c    = flat >> 4;
    int d4   = flat & 15;
    float4 v = reinterpret_cast<const float4*>(src + (size_t)c * D_HEAD)[d4];
    tile[c][d4 * 4 + 0] = v.x;
    tile[c][d4 * 4 + 1] = v.y;
    tile[c][d4 * 4 + 2] = v.z;
    tile[c][d4 * 4 + 3] = v.w;
  }
  __syncthreads();

  int d     = tid >> 2;
  int cpart = (tid & 3) * 16;
  short* dst = Wt + ((size_t)(proj * H_NUM + h) * D_HEAD + d) * C_DIM + cb * 64 + cpart;
  short8 o0, o1;
#pragma unroll
  for (int j = 0; j < 8; j++) {
    o0[j] = f2bf(tile[cpart + j][d]);
    o1[j] = f2bf(tile[cpart + 8 + j][d]);
  }
  *reinterpret_cast<short8*>(dst)     = o0;
  *reinterpret_cast<short8*>(dst + 8) = o1;
}

// ---------------------------------------------------------------------------
// GEMM: C[M,N] = A[M,K] @ Bt[N,K]^T, bf16 in, f32 accum.
// BMTx128 tile, BK=32, linear LDS, global_load_lds width-16, 3-deep staging +
// counted vmcnt. BMT=128 (4 loads/stage) or 64 (3 loads/stage; 2x grid for
// occupancy on small-N out-proj).
// ---------------------------------------------------------------------------
template <int MODE, int BMT>
__global__ __launch_bounds__(256) void gemm_bt(
    const short* __restrict__ A, const short* __restrict__ Bt,
    const float* __restrict__ bias,
    short* __restrict__ qb, short* __restrict__ kb, short* __restrict__ vtb,
    float* __restrict__ outb,
    int M, int N, int K) {
  constexpr int BK = 32;
  constexpr int MR = BMT / 32;       // acc row-tiles per wave
  constexpr int NLA = BMT / 64;      // A-stage loads per thread (1 or 2)
  __shared__ short As[3][BMT * BK];
  __shared__ short Bs[3][128 * BK];

  int tid  = threadIdx.x;
  int lane = tid & 63;
  int wv   = tid >> 6;
  int q15  = lane & 15, g = lane >> 4;
  int ntn  = N >> 7;
  int bm   = blockIdx.x / ntn;
  int bn   = blockIdx.x % ntn;
  int row0 = bm * BMT, col0 = bn << 7;
  int wm   = (wv >> 1) * (BMT / 2);
  int wn   = (wv & 1) << 6;

  f32x4 acc[MR][4];
#pragma unroll
  for (int i = 0; i < MR; i++)
#pragma unroll
    for (int j = 0; j < 4; j++) acc[i][j] = (f32x4){0.f, 0.f, 0.f, 0.f};

  const short* ag = A  + (size_t)(row0 + (tid >> 2)) * K + (tid & 3) * 8;
  const short* bg = Bt + (size_t)(col0 + (tid >> 2)) * K + (tid & 3) * 8;
  const size_t gstep = (size_t)64 * K;

  auto stage = [&](int ks, int buf) {
    const short* a  = ag + (size_t)ks * BK;
    const short* bb = bg + (size_t)ks * BK;
    gld_lds16(&As[buf][0] + tid * 8, a);
    if constexpr (NLA == 2) gld_lds16(&As[buf][64 * BK] + tid * 8, a + gstep);
    gld_lds16(&Bs[buf][0] + tid * 8, bb);
    gld_lds16(&Bs[buf][64 * BK] + tid * 8, bb + gstep);
  };

  int nk = K / BK;
  stage(0, 0);
  stage(1, 1);
  if constexpr (NLA == 2) {
    asm volatile("s_waitcnt vmcnt(4)" ::: "memory");
  } else {
    asm volatile("s_waitcnt vmcnt(3)" ::: "memory");
  }
  __builtin_amdgcn_s_barrier();
  __builtin_amdgcn_sched_barrier(0);

  for (int k = 0; k < nk; ++k) {
    int buf = k % 3;
    if (k + 2 < nk) stage(k + 2, (k + 2) % 3);

    short8 af[MR], bf[4];
#pragma unroll
    for (int mi = 0; mi < MR; mi++)
      af[mi] = *reinterpret_cast<const short8*>(
          &As[buf][(wm + mi * 16 + q15) * BK + g * 8]);
#pragma unroll
    for (int ni = 0; ni < 4; ni++)
      bf[ni] = *reinterpret_cast<const short8*>(
          &Bs[buf][(wn + ni * 16 + q15) * BK + g * 8]);
    __builtin_amdgcn_s_setprio(1);
#pragma unroll
    for (int mi = 0; mi < MR; mi++)
#pragma unroll
      for (int ni = 0; ni < 4; ni++)
        acc[mi][ni] = __builtin_amdgcn_mfma_f32_16x16x32_bf16(af[mi], bf[ni],
                                                              acc[mi][ni], 0, 0, 0);
    __builtin_amdgcn_s_setprio(0);

    if (k + 1 < nk) {
      if (k + 2 < nk) {
        if constexpr (NLA == 2) { BAR_VM(4); } else { BAR_VM(3); }
      } else {
        BAR_VM(0);
      }
    }
  }

  // epilogue: C/D layout: col = lane&15, row = (lane>>4)*4 + r
#pragma unroll
  for (int mi = 0; mi < MR; mi++) {
#pragma unroll
    for (int ni = 0; ni < 4; ni++) {
      int rb  = row0 + wm + mi * 16 + (g << 2);
      int col = col0 + wn + ni * 16 + q15;
      f32x4 v = acc[mi][ni];
      if (MODE == 0) {
        int proj = col >> 10;
        int hh   = (col >> 6) & (H_NUM - 1);
        int d    = col & (D_HEAD - 1);
        int b    = rb >> 11;
        int t    = rb & (T_SEQ - 1);
        if (proj < 2) {
          float scl = (proj == 0) ? 0.125f : 1.0f;  // fold 1/sqrt(D) into q
          short* dst = (proj == 0 ? qb : kb) +
                       ((size_t)(b * H_NUM + hh) * T_SEQ) * D_HEAD + d;
#pragma unroll
          for (int r = 0; r < 4; r++)
            dst[(size_t)(t + r) * D_HEAD] = f2bf(v[r] * scl);
        } else {
          short4v pk;
#pragma unroll
          for (int r = 0; r < 4; r++) pk[r] = f2bf(v[r]);
          short* dst = vtb + ((size_t)(b * H_NUM + hh) * D_HEAD + d) * T_SEQ + t;
          *reinterpret_cast<short4v*>(dst) = pk;
        }
      } else {
        float bb = bias[col];
#pragma unroll
        for (int r = 0; r < 4; r++)
          outb[(size_t)(rb + r) * N + col] = v[r] + bb;
      }
    }
  }
}

// ---------------------------------------------------------------------------
// Flash attention v8: swapped-operand (S^T = K·Q^T), LDS-staged K/V (2-buf,
// 32KB arena, global_load_lds w=16, pre-swizzled source + swizzled ds_read),
// ONE 64-q strip per block -> 1024 blocks = 4 blocks/CU = 4 waves/SIMD
// (launch_bounds(256,4): VGPR<=128; fragments come from LDS so no global-load
// register starvation). Per-CU balance: the 4 co-resident blocks of a CU get
// strips {31-a, a, 31-a, a} -> constant 64 chunk-units. 4 heads per XCD.
// ---------------------------------------------------------------------------
__global__ __launch_bounds__(256, 4) void attn_fwd(const short* __restrict__ qg,
                                                   const short* __restrict__ kg,
                                                   const short* __restrict__ vt,
                                                   short* __restrict__ ob) {
  constexpr float LOG2E = 1.44269504f;
  int bid  = blockIdx.x;
  int q2   = bid >> 8;                  // 0..3 (quartile)
  int r    = bid & 255;
  int bh   = (r & 7) * 4 + q2;          // XCD (bid&7 == r&7) sees 4 heads
  int sb   = r >> 3;                    // 0..31
  int strip = (q2 & 1) ? sb : 31 - sb;  // quartile-alternating: CU sum const
  int b    = bh >> 4;
  int h    = bh & 15;
  int tid  = threadIdx.x, lane = tid & 63, wv = tid >> 6;
  int q15  = lane & 15, g = lane >> 4;
  int qr   = strip * 64 + wv * 16;      // wave's 16 q rows

  // 32KB arena: [K0:4096][K1:4096][V0:4096][V1:4096] shorts; Ol aliased at 0.
  __shared__ short arena[16384];

  const short* qp = qg + (size_t)bh * T_SEQ * D_HEAD;
  const short* kp = kg + (size_t)bh * T_SEQ * D_HEAD;
  const short* vp = vt + (size_t)bh * D_HEAD * T_SEQ;

  // staging geometry (rule #21): LDS written linearly (base + lane*16B);
  // SOURCE colbyte pre-swizzled so data(row, cb) lands at byte row*128 ^ ((row&7)<<4).
  int r8    = lane >> 3;
  int gcb   = ((lane & 7) * 16) ^ (r8 << 4);
  int srow0 = wv * 16;

  // fragment-read offsets (chunk-invariant, shorts)
  int hh = (q15 & 7) << 4;
  int koff0 = ((0 * 64 + g * 16) ^ hh) >> 1;
  int koff1 = ((1 * 64 + g * 16) ^ hh) >> 1;
  int voff[4];
#pragma unroll
  for (int st = 0; st < 4; st++) voff[st] = ((st * 32 + g * 8) ^ hh) >> 1;

  // Q fragment (prescaled by 1/8): lane&15 = q, elems over d
  short8 qf[2];
#pragma unroll
  for (int kk = 0; kk < 2; kk++)
    qf[kk] = *reinterpret_cast<const short8*>(
        qp + (size_t)(qr + q15) * D_HEAD + kk * 32 + g * 8);

  f32x4 acc[4];
#pragma unroll
  for (int dt = 0; dt < 4; dt++) acc[dt] = (f32x4){0.f, 0.f, 0.f, 0.f};
  float m_ = -1e30f, l_ = 0.f;

  int nch = strip + 1;

  auto stage = [&](int c, int pbuf) {
    const short* ks = kp + (size_t)(c * 64 + srow0 + r8) * D_HEAD + (gcb >> 1);
    const short* vs = vp + (size_t)(srow0 + r8) * T_SEQ + c * 64 + (gcb >> 1);
    short* kd = arena + pbuf * 4096 + srow0 * 64 + lane * 8;
    short* vd = arena + 8192 + pbuf * 4096 + srow0 * 64 + lane * 8;
    gld_lds16(kd, ks);
    gld_lds16(kd + 8 * 64, ks + (size_t)8 * D_HEAD);
    gld_lds16(vd, vs);
    gld_lds16(vd + 8 * 64, vs + (size_t)8 * T_SEQ);
  };

  stage(0, 0);
  BAR_VM(0);

  for (int c = 0; c < nch; ++c) {
    int s0 = c * 64;
    if (c + 1 < nch) stage(c + 1, (c + 1) & 1);
    const short* Kb = arena + (c & 1) * 4096;
    const short* Vb = arena + 8192 + (c & 1) * 4096;

    // K fragments (swizzled b128 reads)
    short8 kf[4][2];
#pragma unroll
    for (int st = 0; st < 4; st++) {
      int rbase = (st * 16 + q15) * 64;
      kf[st][0] = *reinterpret_cast<const short8*>(&Kb[rbase + koff0]);
      kf[st][1] = *reinterpret_cast<const short8*>(&Kb[rbase + koff1]);
    }

    // S^T = K·Q^T: D[row=s][col=q]
    f32x4 sv[4];
    __builtin_amdgcn_s_setprio(1);
#pragma unroll
    for (int st = 0; st < 4; st++) {
      f32x4 s = (f32x4){0.f, 0.f, 0.f, 0.f};
      s = __builtin_amdgcn_mfma_f32_16x16x32_bf16(kf[st][0], qf[0], s, 0, 0, 0);
      s = __builtin_amdgcn_mfma_f32_16x16x32_bf16(kf[st][1], qf[1], s, 0, 0, 0);
      sv[st] = s;
    }
    __builtin_amdgcn_s_setprio(0);

    // V fragments (consumed after softmax)
    short4v vf[4][4];  // [st][dt]
#pragma unroll
    for (int st = 0; st < 4; st++)
#pragma unroll
      for (int dt = 0; dt < 4; dt++)
        vf[st][dt] = *reinterpret_cast<const short4v*>(
            &Vb[(dt * 16 + q15) * 64 + voff[st]]);

    // causal mask on last chunk (s <= q)
    if (c == nch - 1) {
#pragma unroll
      for (int st = 0; st < 4; st++)
#pragma unroll
        for (int r2 = 0; r2 < 4; r2++) {
          int sg = s0 + st * 16 + g * 4 + r2;
          if (sg > qr + q15) sv[st][r2] = -1e30f;
        }
    }

    // online softmax (lane-local + 2 shfl), defer-max (T13)
    float mx = sv[0][0];
#pragma unroll
    for (int st = 0; st < 4; st++)
#pragma unroll
      for (int r2 = 0; r2 < 4; r2++) mx = fmaxf(mx, sv[st][r2]);
    mx = fmaxf(mx, __shfl_xor(mx, 16));
    mx = fmaxf(mx, __shfl_xor(mx, 32));
    if (!__all(mx <= m_ + 8.0f)) {
      float mnew = fmaxf(m_, mx);
      float sc   = __builtin_amdgcn_exp2f((m_ - mnew) * LOG2E);
      m_ = mnew;
      l_ *= sc;
#pragma unroll
      for (int dt = 0; dt < 4; dt++) acc[dt] *= sc;
    }
    float mcur = m_;
    short4v pbf[4];
    float ps = 0.f;
#pragma unroll
    for (int st = 0; st < 4; st++)
#pragma unroll
      for (int r2 = 0; r2 < 4; r2++) {
        float p = __builtin_amdgcn_exp2f((sv[st][r2] - mcur) * LOG2E);
        ps += p;
        pbf[st][r2] = f2bf_trunc(p);  // 1-instr truncating cvt
      }
    ps += __shfl_xor(ps, 16);
    ps += __shfl_xor(ps, 32);
    l_ += ps;

    // PV: O^T[d][q] += V^T[d][s] · P^T[s][q], 16-s tiles
    __builtin_amdgcn_s_setprio(1);
#pragma unroll
    for (int st = 0; st < 4; st++)
#pragma unroll
      for (int dt = 0; dt < 4; dt++) {
#if __has_builtin(__builtin_amdgcn_mfma_f32_16x16x16bf16_1k)
        acc[dt] = __builtin_amdgcn_mfma_f32_16x16x16bf16_1k(
            vf[st][dt], pbf[st], acc[dt], 0, 0, 0);
#else
        short4v v4 = vf[st][dt];
        short4v p4 = pbf[st];
        short8 az = (short8){v4[0], v4[1], v4[2], v4[3], 0, 0, 0, 0};
        short8 bz = (short8){p4[0], p4[1], p4[2], p4[3], 0, 0, 0, 0};
        acc[dt] =
            __builtin_amdgcn_mfma_f32_16x16x32_bf16(az, bz, acc[dt], 0, 0, 0);
#endif
      }
    __builtin_amdgcn_s_setprio(0);

    BAR_VM(0);  // stage(c+1) landed; all waves' ds_reads of this buf retired
  }

  // epilogue: per-wave transpose via arena (aliases K0/V0; loop ended with
  // barrier+lgkmcnt(0), safe to overwrite). Wave-local region -> no barrier.
  short* OlW = arena + wv * (16 * 68);
  float inv = 1.0f / l_;
#pragma unroll
  for (int dt = 0; dt < 4; dt++)
#pragma unroll
    for (int r2 = 0; r2 < 4; r2++)
      OlW[q15 * 68 + dt * 16 + g * 4 + r2] = f2bf(acc[dt][r2] * inv);
  int row = lane >> 2, cb = (lane & 3) * 16;
  size_t base = ((size_t)(b * T_SEQ) + qr + row) * C_DIM + h * 64 + cb;
  const short* src = OlW + row * 68 + cb;
  *reinterpret_cast<short8*>(ob + base) = *reinterpret_cast<const short8*>(src);
  *reinterpret_cast<short8*>(ob + base + 8) =
      *reinterpret_cast<const short8*>(src + 8);
}

// ---------------------------------------------------------------------------
// Launch. Workspace layout (needs >= 40 MB):
//   [0, 8M)        xb   bf16 x cast            (reused as obuf after QKV GEMM)
//   [8M, 14.3M)    Wt   bf16 packed QKV weights [3072][1024]
//   [14M, 16M)     Wob  bf16 Wo [1024][1024]
//   [16M, 24M)     qb   bf16 [B,H,T,D]  (prescaled by 1/8)
//   [24M, 32M)     kb   bf16 [B,H,T,D]
//   [32M, 40M)     vtb  bf16 [B,H,D,T]
// ---------------------------------------------------------------------------
extern "C" void kernel_launch(void* const* d_in, const int* in_sizes, int n_in,
                              void* d_out, int out_size, void* d_ws, size_t ws_size,
                              hipStream_t stream) {
  const float* x  = (const float*)d_in[0];
  const float* Wq = (const float*)d_in[1];
  const float* Wk = (const float*)d_in[2];
  const float* Wv = (const float*)d_in[3];
  const float* Wo = (const float*)d_in[4];
  const float* bo = (const float*)d_in[5];
  float* out = (float*)d_out;

  char* ws = (char*)d_ws;
  short* xb   = (short*)(ws + 0);
  short* Wt   = (short*)(ws + 8388608);
  short* Wob  = (short*)(ws + 14680064);
  short* qb   = (short*)(ws + 16777216);
  short* kb   = (short*)(ws + 25165824);
  short* vtb  = (short*)(ws + 33554432);
  short* obuf = xb;  // reuse after QKV GEMM consumed xb

  cvt_f32_bf16<<<2048, 256, 0, stream>>>(x, xb, M_ROWS * C_DIM / 8);
  cvt_f32_bf16<<<512, 256, 0, stream>>>(Wo, Wob, C_DIM * C_DIM / 8);
  pack_w<<<768, 256, 0, stream>>>(Wq, Wk, Wv, Wt);

  gemm_bt<0, 128><<<(M_ROWS / 128) * (N_QKV / 128), 256, 0, stream>>>(
      xb, Wt, nullptr, qb, kb, vtb, nullptr, M_ROWS, N_QKV, C_DIM);

  attn_fwd<<<1024, 256, 0, stream>>>(qb, kb, vtb, obuf);

  gemm_bt<1, 64><<<(M_ROWS / 64) * (C_DIM / 128), 256, 0, stream>>>(
      obuf, Wob, bo, nullptr, nullptr, nullptr, out, M_ROWS, C_DIM, C_DIM);
}

// Round 9
// 115.198 us; speedup vs baseline: 1.1443x; 1.0342x over previous
//
#include <hip/hip_runtime.h>
#include <hip/hip_bf16.h>
#include <cstdint>
#include <math.h>

// Problem constants
#define B_DIM 2
#define T_SEQ 2048
#define C_DIM 1024
#define H_NUM 16
#define D_HEAD 64
#define M_ROWS (B_DIM * T_SEQ)      // 4096
#define N_QKV (3 * H_NUM * D_HEAD)  // 3072

using short8  = __attribute__((ext_vector_type(8))) short;
using short4v = __attribute__((ext_vector_type(4))) short;
using f32x4   = __attribute__((ext_vector_type(4))) float;

__device__ __forceinline__ short f2bf(float f) {
  union { __hip_bfloat16 h; short s; } u;
  u.h = __float2bfloat16(f);
  return u.s;
}

// pack hi16(a),hi16(b) -> one u32 (truncating f32->bf16 pair; safe for p>=0)
__device__ __forceinline__ unsigned pk2bf(float a, float b) {
  union { float f; unsigned u; } ua, ub;
  ua.f = a; ub.f = b;
  // v_perm_b32: S0=b (high dword), S1=a; sel bytes {2,3,6,7} = {a.hi16, b.hi16}
  return __builtin_amdgcn_perm(ub.u, ua.u, 0x07060302u);
}

// async global->LDS, 16B per lane (m97 pattern: per-lane LDS ptr = base + lane*16B)
__device__ __forceinline__ void gld_lds16(short* lds, const short* g) {
  __builtin_amdgcn_global_load_lds(
      (const unsigned int __attribute__((address_space(1)))*)g,
      (unsigned int __attribute__((address_space(3)))*)lds, 16, 0, 0);
}

// counted-vmcnt barrier cluster (T4): loads stay in flight across the barrier.
#define BAR_VM(N)                                                    \
  do {                                                               \
    asm volatile("s_waitcnt vmcnt(" #N ") lgkmcnt(0)" ::: "memory"); \
    __builtin_amdgcn_s_barrier();                                    \
    __builtin_amdgcn_sched_barrier(0);                               \
  } while (0)

// ---------------------------------------------------------------------------
// Kernel 1: f32 -> bf16 cast (vectorized, 8 elems/thread)
// ---------------------------------------------------------------------------
__global__ __launch_bounds__(256) void cvt_f32_bf16(const float* __restrict__ in,
                                                    short* __restrict__ out, int n8) {
  int i = blockIdx.x * 256 + threadIdx.x;
  if (i >= n8) return;
  const float4* p = reinterpret_cast<const float4*>(in) + (size_t)i * 2;
  float4 a = p[0], b = p[1];
  short8 o;
  o[0] = f2bf(a.x); o[1] = f2bf(a.y); o[2] = f2bf(a.z); o[3] = f2bf(a.w);
  o[4] = f2bf(b.x); o[5] = f2bf(b.y); o[6] = f2bf(b.z); o[7] = f2bf(b.w);
  reinterpret_cast<short8*>(out)[i] = o;
}

// ---------------------------------------------------------------------------
// Kernel 2: pack Wq/Wk/Wv [H][C][D] f32 -> Wt [3*H*D][C] bf16 (transposed)
// ---------------------------------------------------------------------------
__global__ __launch_bounds__(256) void pack_w(const float* __restrict__ Wq,
                                              const float* __restrict__ Wk,
                                              const float* __restrict__ Wv,
                                              short* __restrict__ Wt) {
  int bid  = blockIdx.x;
  int proj = bid >> 8;
  int h    = (bid >> 4) & 15;
  int cb   = bid & 15;
  const float* W = (proj == 0) ? Wq : ((proj == 1) ? Wk : Wv);
  const float* src = W + ((size_t)h * C_DIM + (size_t)cb * 64) * D_HEAD;

  __shared__ float tile[64][65];
  int tid = threadIdx.x;

#pragma unroll
  for (int j = 0; j < 4; j++) {
    int flat = tid + j * 256;
    int c    = flat >> 4;
    int d4   = flat & 15;
    float4 v = reinterpret_cast<const float4*>(src + (size_t)c * D_HEAD)[d4];
    tile[c][d4 * 4 + 0] = v.x;
    tile[c][d4 * 4 + 1] = v.y;
    tile[c][d4 * 4 + 2] = v.z;
    tile[c][d4 * 4 + 3] = v.w;
  }
  __syncthreads();

  int d     = tid >> 2;
  int cpart = (tid & 3) * 16;
  short* dst = Wt + ((size_t)(proj * H_NUM + h) * D_HEAD + d) * C_DIM + cb * 64 + cpart;
  short8 o0, o1;
#pragma unroll
  for (int j = 0; j < 8; j++) {
    o0[j] = f2bf(tile[cpart + j][d]);
    o1[j] = f2bf(tile[cpart + 8 + j][d]);
  }
  *reinterpret_cast<short8*>(dst)     = o0;
  *reinterpret_cast<short8*>(dst + 8) = o1;
}

// ---------------------------------------------------------------------------
// GEMM: C[M,N] = A[M,K] @ Bt[N,K]^T, bf16 in, f32 accum.
// BMTx128 tile, BK=32, linear LDS, global_load_lds width-16, 3-deep staging +
// counted vmcnt. BMT=128 (4 loads/stage) or 64 (3 loads/stage).
// ---------------------------------------------------------------------------
template <int MODE, int BMT>
__global__ __launch_bounds__(256) void gemm_bt(
    const short* __restrict__ A, const short* __restrict__ Bt,
    const float* __restrict__ bias,
    short* __restrict__ qb, short* __restrict__ kb, short* __restrict__ vtb,
    float* __restrict__ outb,
    int M, int N, int K) {
  constexpr int BK = 32;
  constexpr int MR = BMT / 32;       // acc row-tiles per wave
  constexpr int NLA = BMT / 64;      // A-stage loads per thread (1 or 2)
  __shared__ short As[3][BMT * BK];
  __shared__ short Bs[3][128 * BK];

  int tid  = threadIdx.x;
  int lane = tid & 63;
  int wv   = tid >> 6;
  int q15  = lane & 15, g = lane >> 4;
  int ntn  = N >> 7;
  int bm   = blockIdx.x / ntn;
  int bn   = blockIdx.x % ntn;
  int row0 = bm * BMT, col0 = bn << 7;
  int wm   = (wv >> 1) * (BMT / 2);
  int wn   = (wv & 1) << 6;

  f32x4 acc[MR][4];
#pragma unroll
  for (int i = 0; i < MR; i++)
#pragma unroll
    for (int j = 0; j < 4; j++) acc[i][j] = (f32x4){0.f, 0.f, 0.f, 0.f};

  const short* ag = A  + (size_t)(row0 + (tid >> 2)) * K + (tid & 3) * 8;
  const short* bg = Bt + (size_t)(col0 + (tid >> 2)) * K + (tid & 3) * 8;
  const size_t gstep = (size_t)64 * K;

  auto stage = [&](int ks, int buf) {
    const short* a  = ag + (size_t)ks * BK;
    const short* bb = bg + (size_t)ks * BK;
    gld_lds16(&As[buf][0] + tid * 8, a);
    if constexpr (NLA == 2) gld_lds16(&As[buf][64 * BK] + tid * 8, a + gstep);
    gld_lds16(&Bs[buf][0] + tid * 8, bb);
    gld_lds16(&Bs[buf][64 * BK] + tid * 8, bb + gstep);
  };

  int nk = K / BK;
  stage(0, 0);
  stage(1, 1);
  if constexpr (NLA == 2) {
    asm volatile("s_waitcnt vmcnt(4)" ::: "memory");
  } else {
    asm volatile("s_waitcnt vmcnt(3)" ::: "memory");
  }
  __builtin_amdgcn_s_barrier();
  __builtin_amdgcn_sched_barrier(0);

  for (int k = 0; k < nk; ++k) {
    int buf = k % 3;
    if (k + 2 < nk) stage(k + 2, (k + 2) % 3);

    short8 af[MR], bf[4];
#pragma unroll
    for (int mi = 0; mi < MR; mi++)
      af[mi] = *reinterpret_cast<const short8*>(
          &As[buf][(wm + mi * 16 + q15) * BK + g * 8]);
#pragma unroll
    for (int ni = 0; ni < 4; ni++)
      bf[ni] = *reinterpret_cast<const short8*>(
          &Bs[buf][(wn + ni * 16 + q15) * BK + g * 8]);
    __builtin_amdgcn_s_setprio(1);
#pragma unroll
    for (int mi = 0; mi < MR; mi++)
#pragma unroll
      for (int ni = 0; ni < 4; ni++)
        acc[mi][ni] = __builtin_amdgcn_mfma_f32_16x16x32_bf16(af[mi], bf[ni],
                                                              acc[mi][ni], 0, 0, 0);
    __builtin_amdgcn_s_setprio(0);

    if (k + 1 < nk) {
      if (k + 2 < nk) {
        if constexpr (NLA == 2) { BAR_VM(4); } else { BAR_VM(3); }
      } else {
        BAR_VM(0);
      }
    }
  }

  // epilogue: C/D layout: col = lane&15, row = (lane>>4)*4 + r
#pragma unroll
  for (int mi = 0; mi < MR; mi++) {
#pragma unroll
    for (int ni = 0; ni < 4; ni++) {
      int rb  = row0 + wm + mi * 16 + (g << 2);
      int col = col0 + wn + ni * 16 + q15;
      f32x4 v = acc[mi][ni];
      if (MODE == 0) {
        int proj = col >> 10;
        int hh   = (col >> 6) & (H_NUM - 1);
        int d    = col & (D_HEAD - 1);
        int b    = rb >> 11;
        int t    = rb & (T_SEQ - 1);
        if (proj < 2) {
          // fold 1/sqrt(D) AND log2(e) into q: softmax runs in log2 domain
          float scl = (proj == 0) ? 0.125f * 1.44269504f : 1.0f;
          short* dst = (proj == 0 ? qb : kb) +
                       ((size_t)(b * H_NUM + hh) * T_SEQ) * D_HEAD + d;
#pragma unroll
          for (int r = 0; r < 4; r++)
            dst[(size_t)(t + r) * D_HEAD] = f2bf(v[r] * scl);
        } else {
          short4v pk;
#pragma unroll
          for (int r = 0; r < 4; r++) pk[r] = f2bf(v[r]);
          short* dst = vtb + ((size_t)(b * H_NUM + hh) * D_HEAD + d) * T_SEQ + t;
          *reinterpret_cast<short4v*>(dst) = pk;
        }
      } else {
        float bb = bias[col];
#pragma unroll
        for (int r = 0; r < 4; r++)
          outb[(size_t)(rb + r) * N + col] = v[r] + bb;
      }
    }
  }
}

// ---------------------------------------------------------------------------
// Flash attention v9: r8 structure (swapped S^T, LDS 2-buf K/V, 1024 blocks =
// 4 blocks/CU, quartile-alternating strips, 4 heads/XCD) with softmax VALU cut:
//   - S in log2 domain (LOG2E folded into Q prescale) -> no per-elem mul
//   - l row-sum via ones-MFMA (off the VALU, off the serial chain)
//   - P bf16 pack via v_perm_b32 (1 instr / pair, truncating)
//   - max tree in v_max3-fusable triples
// ---------------------------------------------------------------------------
__global__ __launch_bounds__(256, 4) void attn_fwd(const short* __restrict__ qg,
                                                   const short* __restrict__ kg,
                                                   const short* __restrict__ vt,
                                                   short* __restrict__ ob) {
  int bid  = blockIdx.x;
  int q2   = bid >> 8;                  // 0..3 (quartile)
  int r    = bid & 255;
  int bh   = (r & 7) * 4 + q2;          // XCD (bid&7) sees 4 heads
  int sb   = r >> 3;                    // 0..31
  int strip = (q2 & 1) ? sb : 31 - sb;  // quartile-alternating: CU sum const
  int b    = bh >> 4;
  int h    = bh & 15;
  int tid  = threadIdx.x, lane = tid & 63, wv = tid >> 6;
  int q15  = lane & 15, g = lane >> 4;
  int qr   = strip * 64 + wv * 16;      // wave's 16 q rows

  // 32KB arena: [K0:4096][K1:4096][V0:4096][V1:4096] shorts; Ol aliased at 0.
  __shared__ short arena[16384];

  const short* qp = qg + (size_t)bh * T_SEQ * D_HEAD;
  const short* kp = kg + (size_t)bh * T_SEQ * D_HEAD;
  const short* vp = vt + (size_t)bh * D_HEAD * T_SEQ;

  // staging geometry (rule #21): LDS written linearly (base + lane*16B);
  // SOURCE colbyte pre-swizzled so data(row, cb) lands at byte row*128 ^ ((row&7)<<4).
  int r8    = lane >> 3;
  int gcb   = ((lane & 7) * 16) ^ (r8 << 4);
  int srow0 = wv * 16;

  // fragment-read offsets (chunk-invariant, shorts)
  int hh = (q15 & 7) << 4;
  int koff0 = ((0 * 64 + g * 16) ^ hh) >> 1;
  int koff1 = ((1 * 64 + g * 16) ^ hh) >> 1;
  int voff[4];
#pragma unroll
  for (int st = 0; st < 4; st++) voff[st] = ((st * 32 + g * 8) ^ hh) >> 1;

  // Q fragment (prescaled by 0.125*log2e): lane&15 = q, elems over d
  short8 qf[2];
#pragma unroll
  for (int kk = 0; kk < 2; kk++)
    qf[kk] = *reinterpret_cast<const short8*>(
        qp + (size_t)(qr + q15) * D_HEAD + kk * 32 + g * 8);

  f32x4 acc[4];
#pragma unroll
  for (int dt = 0; dt < 4; dt++) acc[dt] = (f32x4){0.f, 0.f, 0.f, 0.f};
  f32x4 lacc = (f32x4){0.f, 0.f, 0.f, 0.f};  // l via ones-MFMA; l = lacc[0]
  float m_ = -1e30f;

  const short4v ones4 = (short4v){(short)0x3F80, (short)0x3F80,
                                  (short)0x3F80, (short)0x3F80};  // bf16 1.0

  int nch = strip + 1;

  auto stage = [&](int c, int pbuf) {
    const short* ks = kp + (size_t)(c * 64 + srow0 + r8) * D_HEAD + (gcb >> 1);
    const short* vs = vp + (size_t)(srow0 + r8) * T_SEQ + c * 64 + (gcb >> 1);
    short* kd = arena + pbuf * 4096 + srow0 * 64 + lane * 8;
    short* vd = arena + 8192 + pbuf * 4096 + srow0 * 64 + lane * 8;
    gld_lds16(kd, ks);
    gld_lds16(kd + 8 * 64, ks + (size_t)8 * D_HEAD);
    gld_lds16(vd, vs);
    gld_lds16(vd + 8 * 64, vs + (size_t)8 * T_SEQ);
  };

  stage(0, 0);
  BAR_VM(0);

  for (int c = 0; c < nch; ++c) {
    int s0 = c * 64;
    if (c + 1 < nch) stage(c + 1, (c + 1) & 1);
    const short* Kb = arena + (c & 1) * 4096;
    const short* Vb = arena + 8192 + (c & 1) * 4096;

    // K fragments (swizzled b128 reads)
    short8 kf[4][2];
#pragma unroll
    for (int st = 0; st < 4; st++) {
      int rbase = (st * 16 + q15) * 64;
      kf[st][0] = *reinterpret_cast<const short8*>(&Kb[rbase + koff0]);
      kf[st][1] = *reinterpret_cast<const short8*>(&Kb[rbase + koff1]);
    }

    // S^T = K·Q^T (log2 domain): D[row=s][col=q]
    f32x4 sv[4];
    __builtin_amdgcn_s_setprio(1);
#pragma unroll
    for (int st = 0; st < 4; st++) {
      f32x4 s = (f32x4){0.f, 0.f, 0.f, 0.f};
      s = __builtin_amdgcn_mfma_f32_16x16x32_bf16(kf[st][0], qf[0], s, 0, 0, 0);
      s = __builtin_amdgcn_mfma_f32_16x16x32_bf16(kf[st][1], qf[1], s, 0, 0, 0);
      sv[st] = s;
    }
    __builtin_amdgcn_s_setprio(0);

    // V fragments (consumed after softmax)
    short4v vf[4][4];  // [st][dt]
#pragma unroll
    for (int st = 0; st < 4; st++)
#pragma unroll
      for (int dt = 0; dt < 4; dt++)
        vf[st][dt] = *reinterpret_cast<const short4v*>(
            &Vb[(dt * 16 + q15) * 64 + voff[st]]);

    // causal mask on last chunk (s <= q)
    if (c == nch - 1) {
#pragma unroll
      for (int st = 0; st < 4; st++)
#pragma unroll
        for (int r2 = 0; r2 < 4; r2++) {
          int sg = s0 + st * 16 + g * 4 + r2;
          if (sg > qr + q15) sv[st][r2] = -1e30f;
        }
    }

    // row max: v_max3-fusable triples + 2 shfl across the g-group
    float t0 = fmaxf(fmaxf(sv[0][0], sv[0][1]), sv[0][2]);
    float t1 = fmaxf(fmaxf(sv[0][3], sv[1][0]), sv[1][1]);
    float t2 = fmaxf(fmaxf(sv[1][2], sv[1][3]), sv[2][0]);
    float t3 = fmaxf(fmaxf(sv[2][1], sv[2][2]), sv[2][3]);
    float t4 = fmaxf(fmaxf(sv[3][0], sv[3][1]), sv[3][2]);
    float mx = fmaxf(fmaxf(fmaxf(t0, t1), t2),
                     fmaxf(fmaxf(t3, t4), sv[3][3]));
    mx = fmaxf(mx, __shfl_xor(mx, 16));
    mx = fmaxf(mx, __shfl_xor(mx, 32));

    // defer-max (T13; THR = 8*log2e since log2 domain)
    if (!__all(mx <= m_ + 11.5f)) {
      float mnew = fmaxf(m_, mx);
      float sc   = __builtin_amdgcn_exp2f(m_ - mnew);
      m_ = mnew;
      lacc *= sc;
#pragma unroll
      for (int dt = 0; dt < 4; dt++) acc[dt] *= sc;
    }
    float mcur = m_;

    // p = exp2(s - m); pack pairs via v_perm (truncating bf16, p>=0 safe)
    short4v pbf[4];
#pragma unroll
    for (int st = 0; st < 4; st++) {
      float p0 = __builtin_amdgcn_exp2f(sv[st][0] - mcur);
      float p1 = __builtin_amdgcn_exp2f(sv[st][1] - mcur);
      float p2 = __builtin_amdgcn_exp2f(sv[st][2] - mcur);
      float p3 = __builtin_amdgcn_exp2f(sv[st][3] - mcur);
      union { short4v s; unsigned u[2]; } P;
      P.u[0] = pk2bf(p0, p1);
      P.u[1] = pk2bf(p2, p3);
      pbf[st] = P.s;
    }

    // PV: O^T[d][q] += V^T[d][s]·P^T[s][q]; l row-sum via ones-MFMA
    __builtin_amdgcn_s_setprio(1);
#pragma unroll
    for (int st = 0; st < 4; st++) {
#if __has_builtin(__builtin_amdgcn_mfma_f32_16x16x16bf16_1k)
      lacc = __builtin_amdgcn_mfma_f32_16x16x16bf16_1k(ones4, pbf[st], lacc, 0, 0, 0);
#pragma unroll
      for (int dt = 0; dt < 4; dt++)
        acc[dt] = __builtin_amdgcn_mfma_f32_16x16x16bf16_1k(
            vf[st][dt], pbf[st], acc[dt], 0, 0, 0);
#else
      short4v p4 = pbf[st];
      short8 bz = (short8){p4[0], p4[1], p4[2], p4[3], 0, 0, 0, 0};
      short8 oz = (short8){(short)0x3F80, (short)0x3F80, (short)0x3F80,
                           (short)0x3F80, 0, 0, 0, 0};
      lacc = __builtin_amdgcn_mfma_f32_16x16x32_bf16(oz, bz, lacc, 0, 0, 0);
#pragma unroll
      for (int dt = 0; dt < 4; dt++) {
        short4v v4 = vf[st][dt];
        short8 az = (short8){v4[0], v4[1], v4[2], v4[3], 0, 0, 0, 0};
        acc[dt] =
            __builtin_amdgcn_mfma_f32_16x16x32_bf16(az, bz, acc[dt], 0, 0, 0);
      }
#endif
    }
    __builtin_amdgcn_s_setprio(0);

    BAR_VM(0);  // stage(c+1) landed; all waves' ds_reads of this buf retired
  }

  // epilogue: per-wave transpose via arena (aliases K0; loop ended with
  // barrier+lgkmcnt(0), safe to overwrite). Wave-local region -> no barrier.
  short* OlW = arena + wv * (16 * 68);
  float inv = 1.0f / lacc[0];
#pragma unroll
  for (int dt = 0; dt < 4; dt++)
#pragma unroll
    for (int r2 = 0; r2 < 4; r2++)
      OlW[q15 * 68 + dt * 16 + g * 4 + r2] = f2bf(acc[dt][r2] * inv);
  int row = lane >> 2, cb = (lane & 3) * 16;
  size_t base = ((size_t)(b * T_SEQ) + qr + row) * C_DIM + h * 64 + cb;
  const short* src = OlW + row * 68 + cb;
  *reinterpret_cast<short8*>(ob + base) = *reinterpret_cast<const short8*>(src);
  *reinterpret_cast<short8*>(ob + base + 8) =
      *reinterpret_cast<const short8*>(src + 8);
}

// ---------------------------------------------------------------------------
// Launch. Workspace layout (needs >= 40 MB):
//   [0, 8M)        xb   bf16 x cast            (reused as obuf after QKV GEMM)
//   [8M, 14.3M)    Wt   bf16 packed QKV weights [3072][1024]
//   [14M, 16M)     Wob  bf16 Wo [1024][1024]
//   [16M, 24M)     qb   bf16 [B,H,T,D]  (prescaled by 0.125*log2e)
//   [24M, 32M)     kb   bf16 [B,H,T,D]
//   [32M, 40M)     vtb  bf16 [B,H,D,T]
// ---------------------------------------------------------------------------
extern "C" void kernel_launch(void* const* d_in, const int* in_sizes, int n_in,
                              void* d_out, int out_size, void* d_ws, size_t ws_size,
                              hipStream_t stream) {
  const float* x  = (const float*)d_in[0];
  const float* Wq = (const float*)d_in[1];
  const float* Wk = (const float*)d_in[2];
  const float* Wv = (const float*)d_in[3];
  const float* Wo = (const float*)d_in[4];
  const float* bo = (const float*)d_in[5];
  float* out = (float*)d_out;

  char* ws = (char*)d_ws;
  short* xb   = (short*)(ws + 0);
  short* Wt   = (short*)(ws + 8388608);
  short* Wob  = (short*)(ws + 14680064);
  short* qb   = (short*)(ws + 16777216);
  short* kb   = (short*)(ws + 25165824);
  short* vtb  = (short*)(ws + 33554432);
  short* obuf = xb;  // reuse after QKV GEMM consumed xb

  cvt_f32_bf16<<<2048, 256, 0, stream>>>(x, xb, M_ROWS * C_DIM / 8);
  cvt_f32_bf16<<<512, 256, 0, stream>>>(Wo, Wob, C_DIM * C_DIM / 8);
  pack_w<<<768, 256, 0, stream>>>(Wq, Wk, Wv, Wt);

  gemm_bt<0, 128><<<(M_ROWS / 128) * (N_QKV / 128), 256, 0, stream>>>(
      xb, Wt, nullptr, qb, kb, vtb, nullptr, M_ROWS, N_QKV, C_DIM);

  attn_fwd<<<1024, 256, 0, stream>>>(qb, kb, vtb, obuf);

  gemm_bt<1, 64><<<(M_ROWS / 64) * (C_DIM / 128), 256, 0, stream>>>(
      obuf, Wob, bo, nullptr, nullptr, nullptr, out, M_ROWS, C_DIM, C_DIM);
}

// Round 12
// 110.085 us; speedup vs baseline: 1.1975x; 1.0464x over previous
//
#include <hip/hip_runtime.h>
#include <hip/hip_bf16.h>
#include <cstdint>
#include <math.h>

// Problem constants
#define B_DIM 2
#define T_SEQ 2048
#define C_DIM 1024
#define H_NUM 16
#define D_HEAD 64
#define M_ROWS (B_DIM * T_SEQ)      // 4096
#define N_QKV (3 * H_NUM * D_HEAD)  // 3072

using short8  = __attribute__((ext_vector_type(8))) short;
using short4v = __attribute__((ext_vector_type(4))) short;
using f32x4   = __attribute__((ext_vector_type(4))) float;

__device__ __forceinline__ short f2bf(float f) {
  union { __hip_bfloat16 h; short s; } u;
  u.h = __float2bfloat16(f);
  return u.s;
}

// pack hi16(a),hi16(b) -> one u32 (truncating f32->bf16 pair; safe for p>=0)
__device__ __forceinline__ unsigned pk2bf(float a, float b) {
  union { float f; unsigned u; } ua, ub;
  ua.f = a; ub.f = b;
  return __builtin_amdgcn_perm(ub.u, ua.u, 0x07060302u);
}

// async global->LDS, 16B per lane (m97 pattern: per-lane LDS ptr = base + lane*16B)
__device__ __forceinline__ void gld_lds16(short* lds, const short* g) {
  __builtin_amdgcn_global_load_lds(
      (const unsigned int __attribute__((address_space(1)))*)g,
      (unsigned int __attribute__((address_space(3)))*)lds, 16, 0, 0);
}

// counted-vmcnt barrier cluster (T4): loads stay in flight across the barrier.
#define BAR_VM(N)                                                    \
  do {                                                               \
    asm volatile("s_waitcnt vmcnt(" #N ") lgkmcnt(0)" ::: "memory"); \
    __builtin_amdgcn_s_barrier();                                    \
    __builtin_amdgcn_sched_barrier(0);                               \
  } while (0)

// ---------------------------------------------------------------------------
// Kernel 1: f32 -> bf16 cast (vectorized, 8 elems/thread)
// ---------------------------------------------------------------------------
__global__ __launch_bounds__(256) void cvt_f32_bf16(const float* __restrict__ in,
                                                    short* __restrict__ out, int n8) {
  int i = blockIdx.x * 256 + threadIdx.x;
  if (i >= n8) return;
  const float4* p = reinterpret_cast<const float4*>(in) + (size_t)i * 2;
  float4 a = p[0], b = p[1];
  short8 o;
  o[0] = f2bf(a.x); o[1] = f2bf(a.y); o[2] = f2bf(a.z); o[3] = f2bf(a.w);
  o[4] = f2bf(b.x); o[5] = f2bf(b.y); o[6] = f2bf(b.z); o[7] = f2bf(b.w);
  reinterpret_cast<short8*>(out)[i] = o;
}

// ---------------------------------------------------------------------------
// Kernel 2: pack Wq/Wk/Wv [H][C][D] f32 -> Wt [3*H*D][C] bf16 (transposed)
// ---------------------------------------------------------------------------
__global__ __launch_bounds__(256) void pack_w(const float* __restrict__ Wq,
                                              const float* __restrict__ Wk,
                                              const float* __restrict__ Wv,
                                              short* __restrict__ Wt) {
  int bid  = blockIdx.x;
  int proj = bid >> 8;
  int h    = (bid >> 4) & 15;
  int cb   = bid & 15;
  const float* W = (proj == 0) ? Wq : ((proj == 1) ? Wk : Wv);
  const float* src = W + ((size_t)h * C_DIM + (size_t)cb * 64) * D_HEAD;

  __shared__ float tile[64][65];
  int tid = threadIdx.x;

#pragma unroll
  for (int j = 0; j < 4; j++) {
    int flat = tid + j * 256;
    int c    = flat >> 4;
    int d4   = flat & 15;
    float4 v = reinterpret_cast<const float4*>(src + (size_t)c * D_HEAD)[d4];
    tile[c][d4 * 4 + 0] = v.x;
    tile[c][d4 * 4 + 1] = v.y;
    tile[c][d4 * 4 + 2] = v.z;
    tile[c][d4 * 4 + 3] = v.w;
  }
  __syncthreads();

  int d     = tid >> 2;
  int cpart = (tid & 3) * 16;
  short* dst = Wt + ((size_t)(proj * H_NUM + h) * D_HEAD + d) * C_DIM + cb * 64 + cpart;
  short8 o0, o1;
#pragma unroll
  for (int j = 0; j < 8; j++) {
    o0[j] = f2bf(tile[cpart + j][d]);
    o1[j] = f2bf(tile[cpart + 8 + j][d]);
  }
  *reinterpret_cast<short8*>(dst)     = o0;
  *reinterpret_cast<short8*>(dst + 8) = o1;
}

// ---------------------------------------------------------------------------
// GEMM: C[M,N] = A[M,K] @ Bt[N,K]^T, bf16 in, f32 accum.
// BMTx128 tile, BK=32, linear LDS, global_load_lds width-16, 3-deep staging +
// counted vmcnt, XCD-chunked swizzle (per-XCD bm-stripe swept bn-major).
// MODE 0: LDS-coalesced epilogue (C-tile through the dead staging arena,
//         then 16B coalesced stores; q prescaled by 0.125*log2e).
// MODE 1: bias add, f32 row-major stores (already coalesced).
// ---------------------------------------------------------------------------
template <int MODE, int BMT>
__global__ __launch_bounds__(256) void gemm_bt(
    const short* __restrict__ A, const short* __restrict__ Bt,
    const float* __restrict__ bias,
    short* __restrict__ qb, short* __restrict__ kb, short* __restrict__ vtb,
    float* __restrict__ outb,
    int M, int N, int K) {
  constexpr int BK = 32;
  constexpr int MR = BMT / 32;       // acc row-tiles per wave
  constexpr int NLA = BMT / 64;      // A-stage loads per thread (1 or 2)
  __shared__ short GL[3 * (BMT + 128) * BK];
  short* Asb = GL;                    // 3 * BMT*BK
  short* Bsb = GL + 3 * BMT * BK;     // 3 * 128*BK

  int tid  = threadIdx.x;
  int lane = tid & 63;
  int wv   = tid >> 6;
  int q15  = lane & 15, g = lane >> 4;
  int ntn  = N >> 7;
  // XCD-chunked swizzle: xcd = bid&7; stripe of (M/BMT)/8 bm rows, bn-major.
  int bpx  = (M / BMT) >> 3;                  // bm rows per XCD stripe
  int xcd  = blockIdx.x & 7;
  int idx  = blockIdx.x >> 3;
  int bn   = idx / bpx;
  int bm   = xcd * bpx + (idx - bn * bpx);
  int row0 = bm * BMT, col0 = bn << 7;
  int wm   = (wv >> 1) * (BMT / 2);
  int wn   = (wv & 1) << 6;

  f32x4 acc[MR][4];
#pragma unroll
  for (int i = 0; i < MR; i++)
#pragma unroll
    for (int j = 0; j < 4; j++) acc[i][j] = (f32x4){0.f, 0.f, 0.f, 0.f};

  const short* ag = A  + (size_t)(row0 + (tid >> 2)) * K + (tid & 3) * 8;
  const short* bg = Bt + (size_t)(col0 + (tid >> 2)) * K + (tid & 3) * 8;
  const size_t gstep = (size_t)64 * K;

  auto stage = [&](int ks, int buf) {
    const short* a  = ag + (size_t)ks * BK;
    const short* bb = bg + (size_t)ks * BK;
    gld_lds16(Asb + buf * BMT * BK + tid * 8, a);
    if constexpr (NLA == 2)
      gld_lds16(Asb + buf * BMT * BK + 64 * BK + tid * 8, a + gstep);
    gld_lds16(Bsb + buf * 128 * BK + tid * 8, bb);
    gld_lds16(Bsb + buf * 128 * BK + 64 * BK + tid * 8, bb + gstep);
  };

  int nk = K / BK;
  stage(0, 0);
  stage(1, 1);
  if constexpr (NLA == 2) {
    asm volatile("s_waitcnt vmcnt(4)" ::: "memory");
  } else {
    asm volatile("s_waitcnt vmcnt(3)" ::: "memory");
  }
  __builtin_amdgcn_s_barrier();
  __builtin_amdgcn_sched_barrier(0);

  for (int k = 0; k < nk; ++k) {
    int buf = k % 3;
    if (k + 2 < nk) stage(k + 2, (k + 2) % 3);

    short8 af[MR], bf[4];
#pragma unroll
    for (int mi = 0; mi < MR; mi++)
      af[mi] = *reinterpret_cast<const short8*>(
          &Asb[buf * BMT * BK + (wm + mi * 16 + q15) * BK + g * 8]);
#pragma unroll
    for (int ni = 0; ni < 4; ni++)
      bf[ni] = *reinterpret_cast<const short8*>(
          &Bsb[buf * 128 * BK + (wn + ni * 16 + q15) * BK + g * 8]);
    __builtin_amdgcn_s_setprio(1);
#pragma unroll
    for (int mi = 0; mi < MR; mi++)
#pragma unroll
      for (int ni = 0; ni < 4; ni++)
        acc[mi][ni] = __builtin_amdgcn_mfma_f32_16x16x32_bf16(af[mi], bf[ni],
                                                              acc[mi][ni], 0, 0, 0);
    __builtin_amdgcn_s_setprio(0);

    if (k + 1 < nk) {
      if (k + 2 < nk) {
        if constexpr (NLA == 2) { BAR_VM(4); } else { BAR_VM(3); }
      } else {
        BAR_VM(0);
      }
    }
  }

  // ---------------- epilogue ----------------
  if constexpr (MODE == 0) {
    // C-tile through the (dead) staging arena -> coalesced 16B stores.
    // Tile is 128 t x 128 cols (2 heads); LDT=136 rows stride (17408 shorts
    // <= 24576 arena). [r11 bugfix: was LDT=72 with 128-wide cols -> overlap]
    constexpr int LDT = 136;
    int proj  = col0 >> 10;         // block spans a single projection
    int b     = row0 >> 11;         // single batch per block (128 | 2048)
    int trow0 = row0 & (T_SEQ - 1); // batch-local time offset (r10 bugfix)
    int h0    = (col0 >> 6) & 15;   // first of the 2 heads this block covers
    __syncthreads();                // all waves done reading staging bufs
    if (proj < 2) {
      // q/k: tile [t][d2]; scalar bf16 writes, 16B coalesced reads.
      float scl = (proj == 0) ? 0.125f * 1.44269504f : 1.0f;  // log2-domain q
#pragma unroll
      for (int mi = 0; mi < MR; mi++)
#pragma unroll
        for (int ni = 0; ni < 4; ni++) {
          int t0 = wm + mi * 16 + (g << 2);
          int d2 = wn + ni * 16 + q15;
#pragma unroll
          for (int r = 0; r < 4; r++)
            GL[(t0 + r) * LDT + d2] = f2bf(acc[mi][ni][r] * scl);
        }
      __syncthreads();
      short* dstb = (proj == 0) ? qb : kb;
#pragma unroll
      for (int ps = 0; ps < 8; ps++) {
        int trow  = ps * 16 + (tid >> 4);     // 0..127
        int chunk = tid & 15;                 // 16B chunks across 128 cols
        int hh    = h0 + (chunk >> 3);
        int d     = (chunk & 7) * 8;
        short8 v = *reinterpret_cast<const short8*>(&GL[trow * LDT + chunk * 8]);
        *reinterpret_cast<short8*>(
            dstb + ((size_t)(b * H_NUM + hh) * T_SEQ + trow0 + trow) * D_HEAD + d) = v;
      }
    } else {
      // v: tile [d2][t]; b64 writes (acc has 4 consecutive t), 16B reads.
#pragma unroll
      for (int mi = 0; mi < MR; mi++)
#pragma unroll
        for (int ni = 0; ni < 4; ni++) {
          int t0 = wm + mi * 16 + (g << 2);
          int d2 = wn + ni * 16 + q15;
          short4v pk;
#pragma unroll
          for (int r = 0; r < 4; r++) pk[r] = f2bf(acc[mi][ni][r]);
          *reinterpret_cast<short4v*>(&GL[d2 * LDT + t0]) = pk;
        }
      __syncthreads();
#pragma unroll
      for (int ps = 0; ps < 8; ps++) {
        int drow  = ps * 16 + (tid >> 4);     // 0..127
        int chunk = tid & 15;                 // 16B chunks across 128 t's
        int hh    = h0 + (drow >> 6);
        int d     = drow & 63;
        short8 v = *reinterpret_cast<const short8*>(&GL[drow * LDT + chunk * 8]);
        *reinterpret_cast<short8*>(
            vtb + ((size_t)(b * H_NUM + hh) * D_HEAD + d) * T_SEQ + trow0 +
            chunk * 8) = v;
      }
    }
  } else {
    // out-proj: f32 stores, already coalesced per 16-lane group
#pragma unroll
    for (int mi = 0; mi < MR; mi++) {
#pragma unroll
      for (int ni = 0; ni < 4; ni++) {
        int rb  = row0 + wm + mi * 16 + (g << 2);
        int col = col0 + wn + ni * 16 + q15;
        f32x4 v = acc[mi][ni];
        float bb = bias[col];
#pragma unroll
        for (int r = 0; r < 4; r++)
          outb[(size_t)(rb + r) * N + col] = v[r] + bb;
      }
    }
  }
}

// ---------------------------------------------------------------------------
// Flash attention v9 (unchanged): swapped S^T, LDS 2-buf K/V, 1024 blocks =
// 4 blocks/CU, quartile-alternating strips, 4 heads/XCD, log2-domain softmax,
// ones-MFMA row-sum, v_perm bf16 pack.
// ---------------------------------------------------------------------------
__global__ __launch_bounds__(256, 4) void attn_fwd(const short* __restrict__ qg,
                                                   const short* __restrict__ kg,
                                                   const short* __restrict__ vt,
                                                   short* __restrict__ ob) {
  int bid  = blockIdx.x;
  int q2   = bid >> 8;                  // 0..3 (quartile)
  int r    = bid & 255;
  int bh   = (r & 7) * 4 + q2;          // XCD (bid&7) sees 4 heads
  int sb   = r >> 3;                    // 0..31
  int strip = (q2 & 1) ? sb : 31 - sb;  // quartile-alternating: CU sum const
  int b    = bh >> 4;
  int h    = bh & 15;
  int tid  = threadIdx.x, lane = tid & 63, wv = tid >> 6;
  int q15  = lane & 15, g = lane >> 4;
  int qr   = strip * 64 + wv * 16;      // wave's 16 q rows

  __shared__ short arena[16384];

  const short* qp = qg + (size_t)bh * T_SEQ * D_HEAD;
  const short* kp = kg + (size_t)bh * T_SEQ * D_HEAD;
  const short* vp = vt + (size_t)bh * D_HEAD * T_SEQ;

  int r8    = lane >> 3;
  int gcb   = ((lane & 7) * 16) ^ (r8 << 4);
  int srow0 = wv * 16;

  int hh = (q15 & 7) << 4;
  int koff0 = ((0 * 64 + g * 16) ^ hh) >> 1;
  int koff1 = ((1 * 64 + g * 16) ^ hh) >> 1;
  int voff[4];
#pragma unroll
  for (int st = 0; st < 4; st++) voff[st] = ((st * 32 + g * 8) ^ hh) >> 1;

  short8 qf[2];
#pragma unroll
  for (int kk = 0; kk < 2; kk++)
    qf[kk] = *reinterpret_cast<const short8*>(
        qp + (size_t)(qr + q15) * D_HEAD + kk * 32 + g * 8);

  f32x4 acc[4];
#pragma unroll
  for (int dt = 0; dt < 4; dt++) acc[dt] = (f32x4){0.f, 0.f, 0.f, 0.f};
  f32x4 lacc = (f32x4){0.f, 0.f, 0.f, 0.f};
  float m_ = -1e30f;

  const short4v ones4 = (short4v){(short)0x3F80, (short)0x3F80,
                                  (short)0x3F80, (short)0x3F80};

  int nch = strip + 1;

  auto stage = [&](int c, int pbuf) {
    const short* ks = kp + (size_t)(c * 64 + srow0 + r8) * D_HEAD + (gcb >> 1);
    const short* vs = vp + (size_t)(srow0 + r8) * T_SEQ + c * 64 + (gcb >> 1);
    short* kd = arena + pbuf * 4096 + srow0 * 64 + lane * 8;
    short* vd = arena + 8192 + pbuf * 4096 + srow0 * 64 + lane * 8;
    gld_lds16(kd, ks);
    gld_lds16(kd + 8 * 64, ks + (size_t)8 * D_HEAD);
    gld_lds16(vd, vs);
    gld_lds16(vd + 8 * 64, vs + (size_t)8 * T_SEQ);
  };

  stage(0, 0);
  BAR_VM(0);

  for (int c = 0; c < nch; ++c) {
    int s0 = c * 64;
    if (c + 1 < nch) stage(c + 1, (c + 1) & 1);
    const short* Kb = arena + (c & 1) * 4096;
    const short* Vb = arena + 8192 + (c & 1) * 4096;

    short8 kf[4][2];
#pragma unroll
    for (int st = 0; st < 4; st++) {
      int rbase = (st * 16 + q15) * 64;
      kf[st][0] = *reinterpret_cast<const short8*>(&Kb[rbase + koff0]);
      kf[st][1] = *reinterpret_cast<const short8*>(&Kb[rbase + koff1]);
    }

    f32x4 sv[4];
    __builtin_amdgcn_s_setprio(1);
#pragma unroll
    for (int st = 0; st < 4; st++) {
      f32x4 s = (f32x4){0.f, 0.f, 0.f, 0.f};
      s = __builtin_amdgcn_mfma_f32_16x16x32_bf16(kf[st][0], qf[0], s, 0, 0, 0);
      s = __builtin_amdgcn_mfma_f32_16x16x32_bf16(kf[st][1], qf[1], s, 0, 0, 0);
      sv[st] = s;
    }
    __builtin_amdgcn_s_setprio(0);

    short4v vf[4][4];
#pragma unroll
    for (int st = 0; st < 4; st++)
#pragma unroll
      for (int dt = 0; dt < 4; dt++)
        vf[st][dt] = *reinterpret_cast<const short4v*>(
            &Vb[(dt * 16 + q15) * 64 + voff[st]]);

    if (c == nch - 1) {
#pragma unroll
      for (int st = 0; st < 4; st++)
#pragma unroll
        for (int r2 = 0; r2 < 4; r2++) {
          int sg = s0 + st * 16 + g * 4 + r2;
          if (sg > qr + q15) sv[st][r2] = -1e30f;
        }
    }

    float t0 = fmaxf(fmaxf(sv[0][0], sv[0][1]), sv[0][2]);
    float t1 = fmaxf(fmaxf(sv[0][3], sv[1][0]), sv[1][1]);
    float t2 = fmaxf(fmaxf(sv[1][2], sv[1][3]), sv[2][0]);
    float t3 = fmaxf(fmaxf(sv[2][1], sv[2][2]), sv[2][3]);
    float t4 = fmaxf(fmaxf(sv[3][0], sv[3][1]), sv[3][2]);
    float mx = fmaxf(fmaxf(fmaxf(t0, t1), t2),
                     fmaxf(fmaxf(t3, t4), sv[3][3]));
    mx = fmaxf(mx, __shfl_xor(mx, 16));
    mx = fmaxf(mx, __shfl_xor(mx, 32));

    if (!__all(mx <= m_ + 11.5f)) {
      float mnew = fmaxf(m_, mx);
      float sc   = __builtin_amdgcn_exp2f(m_ - mnew);
      m_ = mnew;
      lacc *= sc;
#pragma unroll
      for (int dt = 0; dt < 4; dt++) acc[dt] *= sc;
    }
    float mcur = m_;

    short4v pbf[4];
#pragma unroll
    for (int st = 0; st < 4; st++) {
      float p0 = __builtin_amdgcn_exp2f(sv[st][0] - mcur);
      float p1 = __builtin_amdgcn_exp2f(sv[st][1] - mcur);
      float p2 = __builtin_amdgcn_exp2f(sv[st][2] - mcur);
      float p3 = __builtin_amdgcn_exp2f(sv[st][3] - mcur);
      union { short4v s; unsigned u[2]; } P;
      P.u[0] = pk2bf(p0, p1);
      P.u[1] = pk2bf(p2, p3);
      pbf[st] = P.s;
    }

    __builtin_amdgcn_s_setprio(1);
#pragma unroll
    for (int st = 0; st < 4; st++) {
#if __has_builtin(__builtin_amdgcn_mfma_f32_16x16x16bf16_1k)
      lacc = __builtin_amdgcn_mfma_f32_16x16x16bf16_1k(ones4, pbf[st], lacc, 0, 0, 0);
#pragma unroll
      for (int dt = 0; dt < 4; dt++)
        acc[dt] = __builtin_amdgcn_mfma_f32_16x16x16bf16_1k(
            vf[st][dt], pbf[st], acc[dt], 0, 0, 0);
#else
      short4v p4 = pbf[st];
      short8 bz = (short8){p4[0], p4[1], p4[2], p4[3], 0, 0, 0, 0};
      short8 oz = (short8){(short)0x3F80, (short)0x3F80, (short)0x3F80,
                           (short)0x3F80, 0, 0, 0, 0};
      lacc = __builtin_amdgcn_mfma_f32_16x16x32_bf16(oz, bz, lacc, 0, 0, 0);
#pragma unroll
      for (int dt = 0; dt < 4; dt++) {
        short4v v4 = vf[st][dt];
        short8 az = (short8){v4[0], v4[1], v4[2], v4[3], 0, 0, 0, 0};
        acc[dt] =
            __builtin_amdgcn_mfma_f32_16x16x32_bf16(az, bz, acc[dt], 0, 0, 0);
      }
#endif
    }
    __builtin_amdgcn_s_setprio(0);

    BAR_VM(0);
  }

  short* OlW = arena + wv * (16 * 68);
  float inv = 1.0f / lacc[0];
#pragma unroll
  for (int dt = 0; dt < 4; dt++)
#pragma unroll
    for (int r2 = 0; r2 < 4; r2++)
      OlW[q15 * 68 + dt * 16 + g * 4 + r2] = f2bf(acc[dt][r2] * inv);
  int row = lane >> 2, cb = (lane & 3) * 16;
  size_t base = ((size_t)(b * T_SEQ) + qr + row) * C_DIM + h * 64 + cb;
  const short* src = OlW + row * 68 + cb;
  *reinterpret_cast<short8*>(ob + base) = *reinterpret_cast<const short8*>(src);
  *reinterpret_cast<short8*>(ob + base + 8) =
      *reinterpret_cast<const short8*>(src + 8);
}

// ---------------------------------------------------------------------------
// Launch. Workspace layout (needs >= 40 MB):
//   [0, 8M)        xb   bf16 x cast            (reused as obuf after QKV GEMM)
//   [8M, 14.3M)    Wt   bf16 packed QKV weights [3072][1024]
//   [14M, 16M)     Wob  bf16 Wo [1024][1024]
//   [16M, 24M)     qb   bf16 [B,H,T,D]  (prescaled by 0.125*log2e)
//   [24M, 32M)     kb   bf16 [B,H,T,D]
//   [32M, 40M)     vtb  bf16 [B,H,D,T]
// ---------------------------------------------------------------------------
extern "C" void kernel_launch(void* const* d_in, const int* in_sizes, int n_in,
                              void* d_out, int out_size, void* d_ws, size_t ws_size,
                              hipStream_t stream) {
  const float* x  = (const float*)d_in[0];
  const float* Wq = (const float*)d_in[1];
  const float* Wk = (const float*)d_in[2];
  const float* Wv = (const float*)d_in[3];
  const float* Wo = (const float*)d_in[4];
  const float* bo = (const float*)d_in[5];
  float* out = (float*)d_out;

  char* ws = (char*)d_ws;
  short* xb   = (short*)(ws + 0);
  short* Wt   = (short*)(ws + 8388608);
  short* Wob  = (short*)(ws + 14680064);
  short* qb   = (short*)(ws + 16777216);
  short* kb   = (short*)(ws + 25165824);
  short* vtb  = (short*)(ws + 33554432);
  short* obuf = xb;  // reuse after QKV GEMM consumed xb

  cvt_f32_bf16<<<2048, 256, 0, stream>>>(x, xb, M_ROWS * C_DIM / 8);
  cvt_f32_bf16<<<512, 256, 0, stream>>>(Wo, Wob, C_DIM * C_DIM / 8);
  pack_w<<<768, 256, 0, stream>>>(Wq, Wk, Wv, Wt);

  gemm_bt<0, 128><<<(M_ROWS / 128) * (N_QKV / 128), 256, 0, stream>>>(
      xb, Wt, nullptr, qb, kb, vtb, nullptr, M_ROWS, N_QKV, C_DIM);

  attn_fwd<<<1024, 256, 0, stream>>>(qb, kb, vtb, obuf);

  gemm_bt<1, 64><<<(M_ROWS / 64) * (C_DIM / 128), 256, 0, stream>>>(
      obuf, Wob, bo, nullptr, nullptr, nullptr, out, M_ROWS, C_DIM, C_DIM);
}

// Round 13
// 108.403 us; speedup vs baseline: 1.2161x; 1.0155x over previous
//
#include <hip/hip_runtime.h>
#include <hip/hip_bf16.h>
#include <cstdint>
#include <math.h>

// Problem constants
#define B_DIM 2
#define T_SEQ 2048
#define C_DIM 1024
#define H_NUM 16
#define D_HEAD 64
#define M_ROWS (B_DIM * T_SEQ)      // 4096
#define N_QKV (3 * H_NUM * D_HEAD)  // 3072

using short8  = __attribute__((ext_vector_type(8))) short;
using short4v = __attribute__((ext_vector_type(4))) short;
using f32x4   = __attribute__((ext_vector_type(4))) float;

__device__ __forceinline__ short f2bf(float f) {
  union { __hip_bfloat16 h; short s; } u;
  u.h = __float2bfloat16(f);
  return u.s;
}

// pack hi16(a),hi16(b) -> one u32 (truncating f32->bf16 pair; safe for p>=0)
__device__ __forceinline__ unsigned pk2bf(float a, float b) {
  union { float f; unsigned u; } ua, ub;
  ua.f = a; ub.f = b;
  return __builtin_amdgcn_perm(ub.u, ua.u, 0x07060302u);
}

// async global->LDS, 16B per lane (m97 pattern: per-lane LDS ptr = base + lane*16B)
__device__ __forceinline__ void gld_lds16(short* lds, const short* g) {
  __builtin_amdgcn_global_load_lds(
      (const unsigned int __attribute__((address_space(1)))*)g,
      (unsigned int __attribute__((address_space(3)))*)lds, 16, 0, 0);
}

// counted-vmcnt barrier cluster (T4): loads stay in flight across the barrier.
#define BAR_VM(N)                                                    \
  do {                                                               \
    asm volatile("s_waitcnt vmcnt(" #N ") lgkmcnt(0)" ::: "memory"); \
    __builtin_amdgcn_s_barrier();                                    \
    __builtin_amdgcn_sched_barrier(0);                               \
  } while (0)

// ---------------------------------------------------------------------------
// Kernel 1: f32 -> bf16 cast (vectorized, 8 elems/thread)
// ---------------------------------------------------------------------------
__global__ __launch_bounds__(256) void cvt_f32_bf16(const float* __restrict__ in,
                                                    short* __restrict__ out, int n8) {
  int i = blockIdx.x * 256 + threadIdx.x;
  if (i >= n8) return;
  const float4* p = reinterpret_cast<const float4*>(in) + (size_t)i * 2;
  float4 a = p[0], b = p[1];
  short8 o;
  o[0] = f2bf(a.x); o[1] = f2bf(a.y); o[2] = f2bf(a.z); o[3] = f2bf(a.w);
  o[4] = f2bf(b.x); o[5] = f2bf(b.y); o[6] = f2bf(b.z); o[7] = f2bf(b.w);
  reinterpret_cast<short8*>(out)[i] = o;
}

// ---------------------------------------------------------------------------
// Kernel 2: pack Wq/Wk/Wv [H][C][D] f32 -> Wt [3*H*D][C] bf16 (transposed)
// ---------------------------------------------------------------------------
__global__ __launch_bounds__(256) void pack_w(const float* __restrict__ Wq,
                                              const float* __restrict__ Wk,
                                              const float* __restrict__ Wv,
                                              short* __restrict__ Wt) {
  int bid  = blockIdx.x;
  int proj = bid >> 8;
  int h    = (bid >> 4) & 15;
  int cb   = bid & 15;
  const float* W = (proj == 0) ? Wq : ((proj == 1) ? Wk : Wv);
  const float* src = W + ((size_t)h * C_DIM + (size_t)cb * 64) * D_HEAD;

  __shared__ float tile[64][65];
  int tid = threadIdx.x;

#pragma unroll
  for (int j = 0; j < 4; j++) {
    int flat = tid + j * 256;
    int c    = flat >> 4;
    int d4   = flat & 15;
    float4 v = reinterpret_cast<const float4*>(src + (size_t)c * D_HEAD)[d4];
    tile[c][d4 * 4 + 0] = v.x;
    tile[c][d4 * 4 + 1] = v.y;
    tile[c][d4 * 4 + 2] = v.z;
    tile[c][d4 * 4 + 3] = v.w;
  }
  __syncthreads();

  int d     = tid >> 2;
  int cpart = (tid & 3) * 16;
  short* dst = Wt + ((size_t)(proj * H_NUM + h) * D_HEAD + d) * C_DIM + cb * 64 + cpart;
  short8 o0, o1;
#pragma unroll
  for (int j = 0; j < 8; j++) {
    o0[j] = f2bf(tile[cpart + j][d]);
    o1[j] = f2bf(tile[cpart + 8 + j][d]);
  }
  *reinterpret_cast<short8*>(dst)     = o0;
  *reinterpret_cast<short8*>(dst + 8) = o1;
}

// ---------------------------------------------------------------------------
// GEMM: C[M,N] = A[M,K] @ Bt[N,K]^T, bf16 in, f32 accum.
// BMTx128 tile, BK=32, linear LDS, global_load_lds width-16, 3-deep staging +
// counted vmcnt, XCD-chunked swizzle, AND one-step register prefetch:
//   per k-step: barrier -> issue ds_reads(k)->regB | stage(k+2) -> MFMA(k-1).
// MFMAs of step k-1 hide step k's ds_read latency; barrier lgkm0 closes the
// buf-reuse race. MODE 0: LDS-coalesced scatter epilogue. MODE 1: bias+f32.
// ---------------------------------------------------------------------------
template <int MODE, int BMT>
__global__ __launch_bounds__(256) void gemm_bt(
    const short* __restrict__ A, const short* __restrict__ Bt,
    const float* __restrict__ bias,
    short* __restrict__ qb, short* __restrict__ kb, short* __restrict__ vtb,
    float* __restrict__ outb,
    int M, int N, int K) {
  constexpr int BK = 32;
  constexpr int MR = BMT / 32;       // acc row-tiles per wave
  constexpr int NLA = BMT / 64;      // A-stage loads per thread (1 or 2)
  __shared__ short GL[3 * (BMT + 128) * BK];
  short* Asb = GL;                    // 3 * BMT*BK
  short* Bsb = GL + 3 * BMT * BK;     // 3 * 128*BK

  int tid  = threadIdx.x;
  int lane = tid & 63;
  int wv   = tid >> 6;
  int q15  = lane & 15, g = lane >> 4;
  int ntn  = N >> 7;
  // XCD-chunked swizzle: xcd = bid&7; stripe of (M/BMT)/8 bm rows, bn-major.
  int bpx  = (M / BMT) >> 3;
  int xcd  = blockIdx.x & 7;
  int idx  = blockIdx.x >> 3;
  int bn   = idx / bpx;
  int bm   = xcd * bpx + (idx - bn * bpx);
  int row0 = bm * BMT, col0 = bn << 7;
  int wm   = (wv >> 1) * (BMT / 2);
  int wn   = (wv & 1) << 6;

  f32x4 acc[MR][4];
#pragma unroll
  for (int i = 0; i < MR; i++)
#pragma unroll
    for (int j = 0; j < 4; j++) acc[i][j] = (f32x4){0.f, 0.f, 0.f, 0.f};

  const short* ag = A  + (size_t)(row0 + (tid >> 2)) * K + (tid & 3) * 8;
  const short* bg = Bt + (size_t)(col0 + (tid >> 2)) * K + (tid & 3) * 8;
  const size_t gstep = (size_t)64 * K;

  auto stage = [&](int ks, int buf) {
    const short* a  = ag + (size_t)ks * BK;
    const short* bb = bg + (size_t)ks * BK;
    gld_lds16(Asb + buf * BMT * BK + tid * 8, a);
    if constexpr (NLA == 2)
      gld_lds16(Asb + buf * BMT * BK + 64 * BK + tid * 8, a + gstep);
    gld_lds16(Bsb + buf * 128 * BK + tid * 8, bb);
    gld_lds16(Bsb + buf * 128 * BK + 64 * BK + tid * 8, bb + gstep);
  };

  auto readf = [&](int ks, short8 (&af)[MR], short8 (&bf)[4]) {
    int buf = ks % 3;
#pragma unroll
    for (int mi = 0; mi < MR; mi++)
      af[mi] = *reinterpret_cast<const short8*>(
          &Asb[buf * BMT * BK + (wm + mi * 16 + q15) * BK + g * 8]);
#pragma unroll
    for (int ni = 0; ni < 4; ni++)
      bf[ni] = *reinterpret_cast<const short8*>(
          &Bsb[buf * 128 * BK + (wn + ni * 16 + q15) * BK + g * 8]);
  };

  auto domfma = [&](short8 (&af)[MR], short8 (&bf)[4]) {
    __builtin_amdgcn_s_setprio(1);
#pragma unroll
    for (int mi = 0; mi < MR; mi++)
#pragma unroll
      for (int ni = 0; ni < 4; ni++)
        acc[mi][ni] = __builtin_amdgcn_mfma_f32_16x16x32_bf16(af[mi], bf[ni],
                                                              acc[mi][ni], 0, 0, 0);
    __builtin_amdgcn_s_setprio(0);
  };

  int nk = K / BK;   // 32 for all our shapes
  short8 fa0[MR], fb0[4], fa1[MR], fb1[4];

  // prologue: stage 0,1; wait stage(0); read frags(0); stage(2)
  stage(0, 0);
  stage(1, 1);
  if constexpr (NLA == 2) {
    asm volatile("s_waitcnt vmcnt(4)" ::: "memory");
  } else {
    asm volatile("s_waitcnt vmcnt(3)" ::: "memory");
  }
  __builtin_amdgcn_s_barrier();
  __builtin_amdgcn_sched_barrier(0);

  readf(0, fa0, fb0);                      // iter 0 (no MFMA yet)
  if (nk > 2) stage(2, 2);
  if (nk > 2) {
    if constexpr (NLA == 2) { BAR_VM(4); } else { BAR_VM(3); }
  } else {
    BAR_VM(0);
  }

  int k = 1;
  for (; k + 1 < nk; k += 2) {
    // iter k: read->set1, MFMA set0 (frags k-1)
    readf(k, fa1, fb1);
    if (k + 2 < nk) stage(k + 2, (k + 2) % 3);
    domfma(fa0, fb0);
    if (k + 2 < nk) {
      if constexpr (NLA == 2) { BAR_VM(4); } else { BAR_VM(3); }
    } else {
      BAR_VM(0);
    }
    // iter k+1: read->set0, MFMA set1 (frags k)
    readf(k + 1, fa0, fb0);
    if (k + 3 < nk) stage(k + 3, (k + 3) % 3);
    domfma(fa1, fb1);
    if (k + 3 < nk) {
      if constexpr (NLA == 2) { BAR_VM(4); } else { BAR_VM(3); }
    } else {
      BAR_VM(0);
    }
  }
  if (k < nk) {  // k == nk-1 (nk even): last read + two trailing MFMAs
    readf(k, fa1, fb1);
    domfma(fa0, fb0);   // frags nk-2
    domfma(fa1, fb1);   // frags nk-1 (compiler inserts lgkm wait)
  } else {
    domfma(fa0, fb0);   // nk odd fallback: trailing MFMA
  }

  // ---------------- epilogue ----------------
  if constexpr (MODE == 0) {
    // C-tile through the (dead) staging arena -> coalesced 16B stores.
    constexpr int LDT = 136;
    int proj  = col0 >> 10;
    int b     = row0 >> 11;
    int trow0 = row0 & (T_SEQ - 1);
    int h0    = (col0 >> 6) & 15;
    __syncthreads();
    if (proj < 2) {
      float scl = (proj == 0) ? 0.125f * 1.44269504f : 1.0f;  // log2-domain q
#pragma unroll
      for (int mi = 0; mi < MR; mi++)
#pragma unroll
        for (int ni = 0; ni < 4; ni++) {
          int t0 = wm + mi * 16 + (g << 2);
          int d2 = wn + ni * 16 + q15;
#pragma unroll
          for (int r = 0; r < 4; r++)
            GL[(t0 + r) * LDT + d2] = f2bf(acc[mi][ni][r] * scl);
        }
      __syncthreads();
      short* dstb = (proj == 0) ? qb : kb;
#pragma unroll
      for (int ps = 0; ps < 8; ps++) {
        int trow  = ps * 16 + (tid >> 4);
        int chunk = tid & 15;
        int hh    = h0 + (chunk >> 3);
        int d     = (chunk & 7) * 8;
        short8 v = *reinterpret_cast<const short8*>(&GL[trow * LDT + chunk * 8]);
        *reinterpret_cast<short8*>(
            dstb + ((size_t)(b * H_NUM + hh) * T_SEQ + trow0 + trow) * D_HEAD + d) = v;
      }
    } else {
#pragma unroll
      for (int mi = 0; mi < MR; mi++)
#pragma unroll
        for (int ni = 0; ni < 4; ni++) {
          int t0 = wm + mi * 16 + (g << 2);
          int d2 = wn + ni * 16 + q15;
          short4v pk;
#pragma unroll
          for (int r = 0; r < 4; r++) pk[r] = f2bf(acc[mi][ni][r]);
          *reinterpret_cast<short4v*>(&GL[d2 * LDT + t0]) = pk;
        }
      __syncthreads();
#pragma unroll
      for (int ps = 0; ps < 8; ps++) {
        int drow  = ps * 16 + (tid >> 4);
        int chunk = tid & 15;
        int hh    = h0 + (drow >> 6);
        int d     = drow & 63;
        short8 v = *reinterpret_cast<const short8*>(&GL[drow * LDT + chunk * 8]);
        *reinterpret_cast<short8*>(
            vtb + ((size_t)(b * H_NUM + hh) * D_HEAD + d) * T_SEQ + trow0 +
            chunk * 8) = v;
      }
    }
  } else {
#pragma unroll
    for (int mi = 0; mi < MR; mi++) {
#pragma unroll
      for (int ni = 0; ni < 4; ni++) {
        int rb  = row0 + wm + mi * 16 + (g << 2);
        int col = col0 + wn + ni * 16 + q15;
        f32x4 v = acc[mi][ni];
        float bb = bias[col];
#pragma unroll
        for (int r = 0; r < 4; r++)
          outb[(size_t)(rb + r) * N + col] = v[r] + bb;
      }
    }
  }
}

// ---------------------------------------------------------------------------
// Flash attention v9 (unchanged): swapped S^T, LDS 2-buf K/V, 1024 blocks =
// 4 blocks/CU, quartile-alternating strips, 4 heads/XCD, log2-domain softmax,
// ones-MFMA row-sum, v_perm bf16 pack.
// ---------------------------------------------------------------------------
__global__ __launch_bounds__(256, 4) void attn_fwd(const short* __restrict__ qg,
                                                   const short* __restrict__ kg,
                                                   const short* __restrict__ vt,
                                                   short* __restrict__ ob) {
  int bid  = blockIdx.x;
  int q2   = bid >> 8;
  int r    = bid & 255;
  int bh   = (r & 7) * 4 + q2;
  int sb   = r >> 3;
  int strip = (q2 & 1) ? sb : 31 - sb;
  int b    = bh >> 4;
  int h    = bh & 15;
  int tid  = threadIdx.x, lane = tid & 63, wv = tid >> 6;
  int q15  = lane & 15, g = lane >> 4;
  int qr   = strip * 64 + wv * 16;

  __shared__ short arena[16384];

  const short* qp = qg + (size_t)bh * T_SEQ * D_HEAD;
  const short* kp = kg + (size_t)bh * T_SEQ * D_HEAD;
  const short* vp = vt + (size_t)bh * D_HEAD * T_SEQ;

  int r8    = lane >> 3;
  int gcb   = ((lane & 7) * 16) ^ (r8 << 4);
  int srow0 = wv * 16;

  int hh = (q15 & 7) << 4;
  int koff0 = ((0 * 64 + g * 16) ^ hh) >> 1;
  int koff1 = ((1 * 64 + g * 16) ^ hh) >> 1;
  int voff[4];
#pragma unroll
  for (int st = 0; st < 4; st++) voff[st] = ((st * 32 + g * 8) ^ hh) >> 1;

  short8 qf[2];
#pragma unroll
  for (int kk = 0; kk < 2; kk++)
    qf[kk] = *reinterpret_cast<const short8*>(
        qp + (size_t)(qr + q15) * D_HEAD + kk * 32 + g * 8);

  f32x4 acc[4];
#pragma unroll
  for (int dt = 0; dt < 4; dt++) acc[dt] = (f32x4){0.f, 0.f, 0.f, 0.f};
  f32x4 lacc = (f32x4){0.f, 0.f, 0.f, 0.f};
  float m_ = -1e30f;

  const short4v ones4 = (short4v){(short)0x3F80, (short)0x3F80,
                                  (short)0x3F80, (short)0x3F80};

  int nch = strip + 1;

  auto stage = [&](int c, int pbuf) {
    const short* ks = kp + (size_t)(c * 64 + srow0 + r8) * D_HEAD + (gcb >> 1);
    const short* vs = vp + (size_t)(srow0 + r8) * T_SEQ + c * 64 + (gcb >> 1);
    short* kd = arena + pbuf * 4096 + srow0 * 64 + lane * 8;
    short* vd = arena + 8192 + pbuf * 4096 + srow0 * 64 + lane * 8;
    gld_lds16(kd, ks);
    gld_lds16(kd + 8 * 64, ks + (size_t)8 * D_HEAD);
    gld_lds16(vd, vs);
    gld_lds16(vd + 8 * 64, vs + (size_t)8 * T_SEQ);
  };

  stage(0, 0);
  BAR_VM(0);

  for (int c = 0; c < nch; ++c) {
    int s0 = c * 64;
    if (c + 1 < nch) stage(c + 1, (c + 1) & 1);
    const short* Kb = arena + (c & 1) * 4096;
    const short* Vb = arena + 8192 + (c & 1) * 4096;

    short8 kf[4][2];
#pragma unroll
    for (int st = 0; st < 4; st++) {
      int rbase = (st * 16 + q15) * 64;
      kf[st][0] = *reinterpret_cast<const short8*>(&Kb[rbase + koff0]);
      kf[st][1] = *reinterpret_cast<const short8*>(&Kb[rbase + koff1]);
    }

    f32x4 sv[4];
    __builtin_amdgcn_s_setprio(1);
#pragma unroll
    for (int st = 0; st < 4; st++) {
      f32x4 s = (f32x4){0.f, 0.f, 0.f, 0.f};
      s = __builtin_amdgcn_mfma_f32_16x16x32_bf16(kf[st][0], qf[0], s, 0, 0, 0);
      s = __builtin_amdgcn_mfma_f32_16x16x32_bf16(kf[st][1], qf[1], s, 0, 0, 0);
      sv[st] = s;
    }
    __builtin_amdgcn_s_setprio(0);

    short4v vf[4][4];
#pragma unroll
    for (int st = 0; st < 4; st++)
#pragma unroll
      for (int dt = 0; dt < 4; dt++)
        vf[st][dt] = *reinterpret_cast<const short4v*>(
            &Vb[(dt * 16 + q15) * 64 + voff[st]]);

    if (c == nch - 1) {
#pragma unroll
      for (int st = 0; st < 4; st++)
#pragma unroll
        for (int r2 = 0; r2 < 4; r2++) {
          int sg = s0 + st * 16 + g * 4 + r2;
          if (sg > qr + q15) sv[st][r2] = -1e30f;
        }
    }

    float t0 = fmaxf(fmaxf(sv[0][0], sv[0][1]), sv[0][2]);
    float t1 = fmaxf(fmaxf(sv[0][3], sv[1][0]), sv[1][1]);
    float t2 = fmaxf(fmaxf(sv[1][2], sv[1][3]), sv[2][0]);
    float t3 = fmaxf(fmaxf(sv[2][1], sv[2][2]), sv[2][3]);
    float t4 = fmaxf(fmaxf(sv[3][0], sv[3][1]), sv[3][2]);
    float mx = fmaxf(fmaxf(fmaxf(t0, t1), t2),
                     fmaxf(fmaxf(t3, t4), sv[3][3]));
    mx = fmaxf(mx, __shfl_xor(mx, 16));
    mx = fmaxf(mx, __shfl_xor(mx, 32));

    if (!__all(mx <= m_ + 11.5f)) {
      float mnew = fmaxf(m_, mx);
      float sc   = __builtin_amdgcn_exp2f(m_ - mnew);
      m_ = mnew;
      lacc *= sc;
#pragma unroll
      for (int dt = 0; dt < 4; dt++) acc[dt] *= sc;
    }
    float mcur = m_;

    short4v pbf[4];
#pragma unroll
    for (int st = 0; st < 4; st++) {
      float p0 = __builtin_amdgcn_exp2f(sv[st][0] - mcur);
      float p1 = __builtin_amdgcn_exp2f(sv[st][1] - mcur);
      float p2 = __builtin_amdgcn_exp2f(sv[st][2] - mcur);
      float p3 = __builtin_amdgcn_exp2f(sv[st][3] - mcur);
      union { short4v s; unsigned u[2]; } P;
      P.u[0] = pk2bf(p0, p1);
      P.u[1] = pk2bf(p2, p3);
      pbf[st] = P.s;
    }

    __builtin_amdgcn_s_setprio(1);
#pragma unroll
    for (int st = 0; st < 4; st++) {
#if __has_builtin(__builtin_amdgcn_mfma_f32_16x16x16bf16_1k)
      lacc = __builtin_amdgcn_mfma_f32_16x16x16bf16_1k(ones4, pbf[st], lacc, 0, 0, 0);
#pragma unroll
      for (int dt = 0; dt < 4; dt++)
        acc[dt] = __builtin_amdgcn_mfma_f32_16x16x16bf16_1k(
            vf[st][dt], pbf[st], acc[dt], 0, 0, 0);
#else
      short4v p4 = pbf[st];
      short8 bz = (short8){p4[0], p4[1], p4[2], p4[3], 0, 0, 0, 0};
      short8 oz = (short8){(short)0x3F80, (short)0x3F80, (short)0x3F80,
                           (short)0x3F80, 0, 0, 0, 0};
      lacc = __builtin_amdgcn_mfma_f32_16x16x32_bf16(oz, bz, lacc, 0, 0, 0);
#pragma unroll
      for (int dt = 0; dt < 4; dt++) {
        short4v v4 = vf[st][dt];
        short8 az = (short8){v4[0], v4[1], v4[2], v4[3], 0, 0, 0, 0};
        acc[dt] =
            __builtin_amdgcn_mfma_f32_16x16x32_bf16(az, bz, acc[dt], 0, 0, 0);
      }
#endif
    }
    __builtin_amdgcn_s_setprio(0);

    BAR_VM(0);
  }

  short* OlW = arena + wv * (16 * 68);
  float inv = 1.0f / lacc[0];
#pragma unroll
  for (int dt = 0; dt < 4; dt++)
#pragma unroll
    for (int r2 = 0; r2 < 4; r2++)
      OlW[q15 * 68 + dt * 16 + g * 4 + r2] = f2bf(acc[dt][r2] * inv);
  int row = lane >> 2, cb = (lane & 3) * 16;
  size_t base = ((size_t)(b * T_SEQ) + qr + row) * C_DIM + h * 64 + cb;
  const short* src = OlW + row * 68 + cb;
  *reinterpret_cast<short8*>(ob + base) = *reinterpret_cast<const short8*>(src);
  *reinterpret_cast<short8*>(ob + base + 8) =
      *reinterpret_cast<const short8*>(src + 8);
}

// ---------------------------------------------------------------------------
// Launch. Workspace layout (needs >= 40 MB):
//   [0, 8M)        xb   bf16 x cast            (reused as obuf after QKV GEMM)
//   [8M, 14.3M)    Wt   bf16 packed QKV weights [3072][1024]
//   [14M, 16M)     Wob  bf16 Wo [1024][1024]
//   [16M, 24M)     qb   bf16 [B,H,T,D]  (prescaled by 0.125*log2e)
//   [24M, 32M)     kb   bf16 [B,H,T,D]
//   [32M, 40M)     vtb  bf16 [B,H,D,T]
// ---------------------------------------------------------------------------
extern "C" void kernel_launch(void* const* d_in, const int* in_sizes, int n_in,
                              void* d_out, int out_size, void* d_ws, size_t ws_size,
                              hipStream_t stream) {
  const float* x  = (const float*)d_in[0];
  const float* Wq = (const float*)d_in[1];
  const float* Wk = (const float*)d_in[2];
  const float* Wv = (const float*)d_in[3];
  const float* Wo = (const float*)d_in[4];
  const float* bo = (const float*)d_in[5];
  float* out = (float*)d_out;

  char* ws = (char*)d_ws;
  short* xb   = (short*)(ws + 0);
  short* Wt   = (short*)(ws + 8388608);
  short* Wob  = (short*)(ws + 14680064);
  short* qb   = (short*)(ws + 16777216);
  short* kb   = (short*)(ws + 25165824);
  short* vtb  = (short*)(ws + 33554432);
  short* obuf = xb;  // reuse after QKV GEMM consumed xb

  cvt_f32_bf16<<<2048, 256, 0, stream>>>(x, xb, M_ROWS * C_DIM / 8);
  cvt_f32_bf16<<<512, 256, 0, stream>>>(Wo, Wob, C_DIM * C_DIM / 8);
  pack_w<<<768, 256, 0, stream>>>(Wq, Wk, Wv, Wt);

  gemm_bt<0, 128><<<(M_ROWS / 128) * (N_QKV / 128), 256, 0, stream>>>(
      xb, Wt, nullptr, qb, kb, vtb, nullptr, M_ROWS, N_QKV, C_DIM);

  attn_fwd<<<1024, 256, 0, stream>>>(qb, kb, vtb, obuf);

  gemm_bt<1, 64><<<(M_ROWS / 64) * (C_DIM / 128), 256, 0, stream>>>(
      obuf, Wob, bo, nullptr, nullptr, nullptr, out, M_ROWS, C_DIM, C_DIM);
}